// Round 9
// baseline (336.800 us; speedup 1.0000x reference)
//
#include <hip/hip_runtime.h>
#include <hip/hip_bf16.h>
#include <math.h>

#define DMODEL  1024
#define DINNER  2048
#define DSTATE  16
#define DCONV   4
#define DTRANK  64
#define NH      8
#define PH      256
#define TOTOUT  4416
#define NPAD    4608            // W_in rows padded to 256 multiple (zeros 4416..4607)
#define NTOT    6656            // [W_in 4416 | pad 192 | W_res 2048] = 26*256
#define MB_ROWS 4096            // rows per batch
#define LC      64              // scan chunk length
#define NCB     (MB_ROWS/LC)    // 64 chunks per batch

typedef __attribute__((ext_vector_type(8))) short bf16x8;
typedef __attribute__((ext_vector_type(4))) float f32x4;

__device__ inline unsigned cvt2bf(float lo, float hi) {
    unsigned r;
    asm("v_cvt_pk_bf16_f32 %0, %1, %2" : "=v"(r) : "v"(lo), "v"(hi));
    return r;
}
__device__ inline ushort f2bf(float v) { return (ushort)(cvt2bf(v, v) & 0xffffu); }
__device__ inline float bf2f(ushort u) {
    union { unsigned u; float f; } w; w.u = (unsigned)u << 16; return w.f;
}
__device__ inline void gload16(const ushort* g, ushort* l) {
    __builtin_amdgcn_global_load_lds((const __attribute__((address_space(1))) unsigned*)(const void*)g,
                                     (__attribute__((address_space(3))) unsigned*)(void*)l, 16, 0, 0);
}

// ---------------- fp32 -> bf16 convert ----------------
__global__ __launch_bounds__(256) void cvt_bf(const float* __restrict__ s,
                                              ushort* __restrict__ d) {
    size_t i = ((size_t)blockIdx.x * 256 + threadIdx.x) * 8;
    float4 v0 = *(const float4*)(s + i);
    float4 v1 = *(const float4*)(s + i + 4);
    uint4 o;
    o.x = cvt2bf(v0.x, v0.y); o.y = cvt2bf(v0.z, v0.w);
    o.z = cvt2bf(v1.x, v1.y); o.w = cvt2bf(v1.z, v1.w);
    *(uint4*)(d + i) = o;
}

// ---------------- fused weight convert: [W_in | pad | W_res] (NTOT rows) + W_out ----------------
__global__ __launch_bounds__(256) void cvt_weights(const float* __restrict__ W_in,
                                                   const float* __restrict__ W_res,
                                                   const float* __restrict__ W_out,
                                                   ushort* __restrict__ dst) {
    const size_t E0 = (size_t)TOTOUT * DMODEL;
    const size_t E1 = (size_t)NPAD * DMODEL;
    const size_t E2 = (size_t)NTOT * DMODEL;
    size_t i = ((size_t)blockIdx.x * 256 + threadIdx.x) * 8;
    float4 v0, v1;
    if (i < E1) {
        if (i < E0) { v0 = *(const float4*)(W_in + i); v1 = *(const float4*)(W_in + i + 4); }
        else { v0 = make_float4(0.f,0.f,0.f,0.f); v1 = v0; }
    } else if (i < E2) {
        size_t o = i - E1; v0 = *(const float4*)(W_res + o); v1 = *(const float4*)(W_res + o + 4);
    } else {
        size_t o = i - E2; v0 = *(const float4*)(W_out + o); v1 = *(const float4*)(W_out + o + 4);
    }
    uint4 o;
    o.x = cvt2bf(v0.x, v0.y); o.y = cvt2bf(v0.z, v0.w);
    o.z = cvt2bf(v1.x, v1.y); o.w = cvt2bf(v1.z, v1.w);
    *(uint4*)(dst + i) = o;
}

// ================= 256x256 bf16 MFMA GEMM: 4-phase K-slab pipeline =================
// dbuf = one K64 tile: A region = 4 slabs x 8KB (slab p: [256 rows][16 k], thread t's 16B
// at slab + t*16 => row t>>1, k-half t&1, with h ^= (r>>2)&1 bank swizzle inside the slab).
// Phases (kk,mh): stage 1 slab of T_{k+1}; ds_read frags; 16 MFMA. Counted vmcnt(4)
// waits only at half boundaries (2 barriers per K-tile). 8 waves 2Mx4N, 128x64/wave.
__global__ __launch_bounds__(512, 2) void gemm_big8(const ushort* __restrict__ A,
                                                    const ushort* __restrict__ W,
                                                    ushort* __restrict__ Zb,
                                                    ushort* __restrict__ Ub,
                                                    float* __restrict__ DBCp,
                                                    ushort* __restrict__ RESb,
                                                    int ntx, int K) {
    __shared__ __align__(16) ushort L[2 * 32768];   // 2 dbuf x 64KB = 128KB
    const int nwg  = gridDim.x;
    const int orig = blockIdx.x;
    const int swz  = (orig & 7) * (nwg >> 3) + (orig >> 3);   // bijective: nwg % 8 == 0
    const int bx = swz % ntx, by = swz / ntx;
    const int row0 = by * 256, col0 = bx * 256;

    const int t    = threadIdx.x;
    const int lane = t & 63, w = t >> 6;
    const int wr   = w >> 2, wc = w & 3;       // 2 M-waves x 4 N-waves, 128x64 per wave
    const int l15  = lane & 15, l4 = lane >> 4;

    // staging: thread t covers row r = t>>1, k-chunk hp = t&1 of each slab; swizzled source
    const int r  = t >> 1, hp = t & 1;
    const int kb = hp ^ ((r >> 2) & 1);        // bank-swizzle flip (involution within slab)
    const ushort* sA = A + (size_t)(row0 + r) * K + kb * 8;
    const ushort* sB = W + (size_t)(col0 + r) * K + kb * 8;
    const int ldst = t * 8;                    // ushort offset within slab (= lane x 16B)

#define STG(d, p, ko) do { \
    gload16(sA + (ko) + (p) * 16, &L[(d) * 32768 + (p) * 4096 + ldst]); \
    gload16(sB + (ko) + (p) * 16, &L[(d) * 32768 + 16384 + (p) * 4096 + ldst]); } while (0)

    // fragment read offsets (ushort), kk=0; kk=1 adds 8192 (2 slabs)
    int offA[8], offB[4];
    #pragma unroll
    for (int mi = 0; mi < 8; mi++) {
        int R = wr * 128 + mi * 16 + l15;
        offA[mi] = (l4 >> 1) * 4096 + R * 16 + (((l4 & 1) ^ ((R >> 2) & 1)) * 8);
    }
    #pragma unroll
    for (int ni = 0; ni < 4; ni++) {
        int R = wc * 64 + ni * 16 + l15;
        offB[ni] = 16384 + (l4 >> 1) * 4096 + R * 16 + (((l4 & 1) ^ ((R >> 2) & 1)) * 8);
    }

    f32x4 acc[8][4];
    #pragma unroll
    for (int i = 0; i < 8; i++)
        #pragma unroll
        for (int j = 0; j < 4; j++)
            acc[i][j] = (f32x4){0.f, 0.f, 0.f, 0.f};

    const int KT = K >> 6;
    // prologue: stage T0 (slab order 0..3)
    STG(0, 0, 0); STG(0, 1, 0); STG(0, 2, 0); STG(0, 3, 0);
    asm volatile("s_waitcnt vmcnt(4)" ::: "memory");   // T0 half0 landed; half1 in flight
    __builtin_amdgcn_sched_barrier(0);
    __builtin_amdgcn_s_barrier();
    __builtin_amdgcn_sched_barrier(0);

    for (int kt = 0; kt < KT; ++kt) {
        const int d = kt & 1;
        const bool pre = (kt + 1) < KT;
        const int ko = (kt + 1) << 6;
        const ushort* Lp = &L[d * 32768];
        bf16x8 af0, af1, af2, af3, bw0, bw1, bw2, bw3;

        // ---- phase 0: (kk=0, mi 0-3) ----
        if (pre) STG(d ^ 1, 0, ko);
        bw0 = *(const bf16x8*)(Lp + offB[0]); bw1 = *(const bf16x8*)(Lp + offB[1]);
        bw2 = *(const bf16x8*)(Lp + offB[2]); bw3 = *(const bf16x8*)(Lp + offB[3]);
        af0 = *(const bf16x8*)(Lp + offA[0]); af1 = *(const bf16x8*)(Lp + offA[1]);
        af2 = *(const bf16x8*)(Lp + offA[2]); af3 = *(const bf16x8*)(Lp + offA[3]);
        __builtin_amdgcn_s_setprio(1);
        acc[0][0] = __builtin_amdgcn_mfma_f32_16x16x32_bf16(af0, bw0, acc[0][0], 0, 0, 0);
        acc[0][1] = __builtin_amdgcn_mfma_f32_16x16x32_bf16(af0, bw1, acc[0][1], 0, 0, 0);
        acc[0][2] = __builtin_amdgcn_mfma_f32_16x16x32_bf16(af0, bw2, acc[0][2], 0, 0, 0);
        acc[0][3] = __builtin_amdgcn_mfma_f32_16x16x32_bf16(af0, bw3, acc[0][3], 0, 0, 0);
        acc[1][0] = __builtin_amdgcn_mfma_f32_16x16x32_bf16(af1, bw0, acc[1][0], 0, 0, 0);
        acc[1][1] = __builtin_amdgcn_mfma_f32_16x16x32_bf16(af1, bw1, acc[1][1], 0, 0, 0);
        acc[1][2] = __builtin_amdgcn_mfma_f32_16x16x32_bf16(af1, bw2, acc[1][2], 0, 0, 0);
        acc[1][3] = __builtin_amdgcn_mfma_f32_16x16x32_bf16(af1, bw3, acc[1][3], 0, 0, 0);
        acc[2][0] = __builtin_amdgcn_mfma_f32_16x16x32_bf16(af2, bw0, acc[2][0], 0, 0, 0);
        acc[2][1] = __builtin_amdgcn_mfma_f32_16x16x32_bf16(af2, bw1, acc[2][1], 0, 0, 0);
        acc[2][2] = __builtin_amdgcn_mfma_f32_16x16x32_bf16(af2, bw2, acc[2][2], 0, 0, 0);
        acc[2][3] = __builtin_amdgcn_mfma_f32_16x16x32_bf16(af2, bw3, acc[2][3], 0, 0, 0);
        acc[3][0] = __builtin_amdgcn_mfma_f32_16x16x32_bf16(af3, bw0, acc[3][0], 0, 0, 0);
        acc[3][1] = __builtin_amdgcn_mfma_f32_16x16x32_bf16(af3, bw1, acc[3][1], 0, 0, 0);
        acc[3][2] = __builtin_amdgcn_mfma_f32_16x16x32_bf16(af3, bw2, acc[3][2], 0, 0, 0);
        acc[3][3] = __builtin_amdgcn_mfma_f32_16x16x32_bf16(af3, bw3, acc[3][3], 0, 0, 0);
        __builtin_amdgcn_s_setprio(0);

        // ---- phase 1: (kk=0, mi 4-7) ----
        if (pre) STG(d ^ 1, 1, ko);
        af0 = *(const bf16x8*)(Lp + offA[4]); af1 = *(const bf16x8*)(Lp + offA[5]);
        af2 = *(const bf16x8*)(Lp + offA[6]); af3 = *(const bf16x8*)(Lp + offA[7]);
        __builtin_amdgcn_s_setprio(1);
        acc[4][0] = __builtin_amdgcn_mfma_f32_16x16x32_bf16(af0, bw0, acc[4][0], 0, 0, 0);
        acc[4][1] = __builtin_amdgcn_mfma_f32_16x16x32_bf16(af0, bw1, acc[4][1], 0, 0, 0);
        acc[4][2] = __builtin_amdgcn_mfma_f32_16x16x32_bf16(af0, bw2, acc[4][2], 0, 0, 0);
        acc[4][3] = __builtin_amdgcn_mfma_f32_16x16x32_bf16(af0, bw3, acc[4][3], 0, 0, 0);
        acc[5][0] = __builtin_amdgcn_mfma_f32_16x16x32_bf16(af1, bw0, acc[5][0], 0, 0, 0);
        acc[5][1] = __builtin_amdgcn_mfma_f32_16x16x32_bf16(af1, bw1, acc[5][1], 0, 0, 0);
        acc[5][2] = __builtin_amdgcn_mfma_f32_16x16x32_bf16(af1, bw2, acc[5][2], 0, 0, 0);
        acc[5][3] = __builtin_amdgcn_mfma_f32_16x16x32_bf16(af1, bw3, acc[5][3], 0, 0, 0);
        acc[6][0] = __builtin_amdgcn_mfma_f32_16x16x32_bf16(af2, bw0, acc[6][0], 0, 0, 0);
        acc[6][1] = __builtin_amdgcn_mfma_f32_16x16x32_bf16(af2, bw1, acc[6][1], 0, 0, 0);
        acc[6][2] = __builtin_amdgcn_mfma_f32_16x16x32_bf16(af2, bw2, acc[6][2], 0, 0, 0);
        acc[6][3] = __builtin_amdgcn_mfma_f32_16x16x32_bf16(af2, bw3, acc[6][3], 0, 0, 0);
        acc[7][0] = __builtin_amdgcn_mfma_f32_16x16x32_bf16(af3, bw0, acc[7][0], 0, 0, 0);
        acc[7][1] = __builtin_amdgcn_mfma_f32_16x16x32_bf16(af3, bw1, acc[7][1], 0, 0, 0);
        acc[7][2] = __builtin_amdgcn_mfma_f32_16x16x32_bf16(af3, bw2, acc[7][2], 0, 0, 0);
        acc[7][3] = __builtin_amdgcn_mfma_f32_16x16x32_bf16(af3, bw3, acc[7][3], 0, 0, 0);
        __builtin_amdgcn_s_setprio(0);

        // ---- W2: dbuf d half1 (slabs 2-3) must be landed ----
        if (pre) { asm volatile("s_waitcnt vmcnt(4)" ::: "memory"); }
        else     { asm volatile("s_waitcnt vmcnt(0)" ::: "memory"); }
        __builtin_amdgcn_sched_barrier(0);
        __builtin_amdgcn_s_barrier();
        __builtin_amdgcn_sched_barrier(0);

        // ---- phase 2: (kk=1, mi 0-3) ----
        if (pre) STG(d ^ 1, 2, ko);
        bw0 = *(const bf16x8*)(Lp + 8192 + offB[0]); bw1 = *(const bf16x8*)(Lp + 8192 + offB[1]);
        bw2 = *(const bf16x8*)(Lp + 8192 + offB[2]); bw3 = *(const bf16x8*)(Lp + 8192 + offB[3]);
        af0 = *(const bf16x8*)(Lp + 8192 + offA[0]); af1 = *(const bf16x8*)(Lp + 8192 + offA[1]);
        af2 = *(const bf16x8*)(Lp + 8192 + offA[2]); af3 = *(const bf16x8*)(Lp + 8192 + offA[3]);
        __builtin_amdgcn_s_setprio(1);
        acc[0][0] = __builtin_amdgcn_mfma_f32_16x16x32_bf16(af0, bw0, acc[0][0], 0, 0, 0);
        acc[0][1] = __builtin_amdgcn_mfma_f32_16x16x32_bf16(af0, bw1, acc[0][1], 0, 0, 0);
        acc[0][2] = __builtin_amdgcn_mfma_f32_16x16x32_bf16(af0, bw2, acc[0][2], 0, 0, 0);
        acc[0][3] = __builtin_amdgcn_mfma_f32_16x16x32_bf16(af0, bw3, acc[0][3], 0, 0, 0);
        acc[1][0] = __builtin_amdgcn_mfma_f32_16x16x32_bf16(af1, bw0, acc[1][0], 0, 0, 0);
        acc[1][1] = __builtin_amdgcn_mfma_f32_16x16x32_bf16(af1, bw1, acc[1][1], 0, 0, 0);
        acc[1][2] = __builtin_amdgcn_mfma_f32_16x16x32_bf16(af1, bw2, acc[1][2], 0, 0, 0);
        acc[1][3] = __builtin_amdgcn_mfma_f32_16x16x32_bf16(af1, bw3, acc[1][3], 0, 0, 0);
        acc[2][0] = __builtin_amdgcn_mfma_f32_16x16x32_bf16(af2, bw0, acc[2][0], 0, 0, 0);
        acc[2][1] = __builtin_amdgcn_mfma_f32_16x16x32_bf16(af2, bw1, acc[2][1], 0, 0, 0);
        acc[2][2] = __builtin_amdgcn_mfma_f32_16x16x32_bf16(af2, bw2, acc[2][2], 0, 0, 0);
        acc[2][3] = __builtin_amdgcn_mfma_f32_16x16x32_bf16(af2, bw3, acc[2][3], 0, 0, 0);
        acc[3][0] = __builtin_amdgcn_mfma_f32_16x16x32_bf16(af3, bw0, acc[3][0], 0, 0, 0);
        acc[3][1] = __builtin_amdgcn_mfma_f32_16x16x32_bf16(af3, bw1, acc[3][1], 0, 0, 0);
        acc[3][2] = __builtin_amdgcn_mfma_f32_16x16x32_bf16(af3, bw2, acc[3][2], 0, 0, 0);
        acc[3][3] = __builtin_amdgcn_mfma_f32_16x16x32_bf16(af3, bw3, acc[3][3], 0, 0, 0);
        __builtin_amdgcn_s_setprio(0);

        // ---- phase 3: (kk=1, mi 4-7) ----
        if (pre) STG(d ^ 1, 3, ko);
        af0 = *(const bf16x8*)(Lp + 8192 + offA[4]); af1 = *(const bf16x8*)(Lp + 8192 + offA[5]);
        af2 = *(const bf16x8*)(Lp + 8192 + offA[6]); af3 = *(const bf16x8*)(Lp + 8192 + offA[7]);
        __builtin_amdgcn_s_setprio(1);
        acc[4][0] = __builtin_amdgcn_mfma_f32_16x16x32_bf16(af0, bw0, acc[4][0], 0, 0, 0);
        acc[4][1] = __builtin_amdgcn_mfma_f32_16x16x32_bf16(af0, bw1, acc[4][1], 0, 0, 0);
        acc[4][2] = __builtin_amdgcn_mfma_f32_16x16x32_bf16(af0, bw2, acc[4][2], 0, 0, 0);
        acc[4][3] = __builtin_amdgcn_mfma_f32_16x16x32_bf16(af0, bw3, acc[4][3], 0, 0, 0);
        acc[5][0] = __builtin_amdgcn_mfma_f32_16x16x32_bf16(af1, bw0, acc[5][0], 0, 0, 0);
        acc[5][1] = __builtin_amdgcn_mfma_f32_16x16x32_bf16(af1, bw1, acc[5][1], 0, 0, 0);
        acc[5][2] = __builtin_amdgcn_mfma_f32_16x16x32_bf16(af1, bw2, acc[5][2], 0, 0, 0);
        acc[5][3] = __builtin_amdgcn_mfma_f32_16x16x32_bf16(af1, bw3, acc[5][3], 0, 0, 0);
        acc[6][0] = __builtin_amdgcn_mfma_f32_16x16x32_bf16(af2, bw0, acc[6][0], 0, 0, 0);
        acc[6][1] = __builtin_amdgcn_mfma_f32_16x16x32_bf16(af2, bw1, acc[6][1], 0, 0, 0);
        acc[6][2] = __builtin_amdgcn_mfma_f32_16x16x32_bf16(af2, bw2, acc[6][2], 0, 0, 0);
        acc[6][3] = __builtin_amdgcn_mfma_f32_16x16x32_bf16(af2, bw3, acc[6][3], 0, 0, 0);
        acc[7][0] = __builtin_amdgcn_mfma_f32_16x16x32_bf16(af3, bw0, acc[7][0], 0, 0, 0);
        acc[7][1] = __builtin_amdgcn_mfma_f32_16x16x32_bf16(af3, bw1, acc[7][1], 0, 0, 0);
        acc[7][2] = __builtin_amdgcn_mfma_f32_16x16x32_bf16(af3, bw2, acc[7][2], 0, 0, 0);
        acc[7][3] = __builtin_amdgcn_mfma_f32_16x16x32_bf16(af3, bw3, acc[7][3], 0, 0, 0);
        __builtin_amdgcn_s_setprio(0);

        // ---- W1: next dbuf half0 (slabs 0-1) must be landed ----
        if (pre) { asm volatile("s_waitcnt vmcnt(4)" ::: "memory"); }
        else     { asm volatile("s_waitcnt vmcnt(0)" ::: "memory"); }
        __builtin_amdgcn_sched_barrier(0);
        __builtin_amdgcn_s_barrier();
        __builtin_amdgcn_sched_barrier(0);
    }
#undef STG

    // epilogue: C/D col=lane&15, row=(lane>>4)*4+reg [m89/m91]; boundaries 256-aligned
    #pragma unroll
    for (int mi = 0; mi < 8; mi++) {
        #pragma unroll
        for (int ni = 0; ni < 4; ni++) {
            #pragma unroll
            for (int rr = 0; rr < 4; rr++) {
                const int row = row0 + wr * 128 + mi * 16 + l4 * 4 + rr;
                const int col = col0 + wc * 64 + ni * 16 + l15;
                const float v = acc[mi][ni][rr];
                if (col0 < DINNER) {
                    Zb[(size_t)row * DINNER + col] = f2bf(v);
                } else if (col0 < 2 * DINNER) {
                    Ub[(size_t)row * DINNER + (col - DINNER)] = f2bf(v);
                } else if (col0 < NPAD) {
                    if (col < TOTOUT)
                        DBCp[(size_t)row * 320 + (col - 2 * DINNER)] = v;
                } else {
                    RESb[(size_t)row * DINNER + (col - NPAD)] = f2bf(v);
                }
            }
        }
    }
}

// ================= 256x128 bf16 MFMA GEMM (round-7 proven), fp32 out =================
__global__ __launch_bounds__(512) void gemm_out(const ushort* __restrict__ A,
                                                const ushort* __restrict__ W,
                                                float* __restrict__ C0,
                                                int ntx, int K, int ldc) {
    __shared__ __align__(16) ushort L[3 * 12288];
    const int nwg  = gridDim.x;
    const int orig = blockIdx.x;
    const int swz  = (orig & 7) * (nwg >> 3) + (orig >> 3);
    const int bx = swz % ntx, by = swz / ntx;
    const int row0 = by * 256, col0 = bx * 128;

    const int t    = threadIdx.x;
    const int lane = t & 63, w = t >> 6;
    const int wr   = w >> 1, wc = w & 1;
    const int l15  = lane & 15, l4 = lane >> 4;

    const int r0g = t >> 2, s0g = t & 3;
    const int r1g = r0g + 128;
    const int rr0 = r0g ^ ((r0g >> 3) & 1), cc0 = s0g ^ ((r0g >> 1) & 3);
    const int rr1 = r1g ^ ((r1g >> 3) & 1), cc1 = s0g ^ ((r1g >> 1) & 3);
    const ushort* sA0 = A + (size_t)(row0 + rr0) * K + cc0 * 8;
    const ushort* sA1 = A + (size_t)(row0 + rr1) * K + cc1 * 8;
    const ushort* sB0 = W + (size_t)(col0 + rr0) * K + cc0 * 8;

    int offA[4], offB[4];
    #pragma unroll
    for (int mi = 0; mi < 4; mi++) {
        int rq = wr * 64 + mi * 16 + l15;
        offA[mi] = (rq * 32 + l4 * 8) ^ (((rq >> 1) & 7) << 3);
    }
    #pragma unroll
    for (int ni = 0; ni < 4; ni++) {
        int rq = wc * 64 + ni * 16 + l15;
        offB[ni] = 8192 + ((rq * 32 + l4 * 8) ^ (((rq >> 1) & 7) << 3));
    }

    f32x4 acc[4][4];
    #pragma unroll
    for (int i = 0; i < 4; i++)
        #pragma unroll
        for (int j = 0; j < 4; j++)
            acc[i][j] = (f32x4){0.f, 0.f, 0.f, 0.f};

    const int KT = K >> 5;
    gload16(sA0,      &L[t * 8]);
    gload16(sA1,      &L[4096 + t * 8]);
    gload16(sB0,      &L[8192 + t * 8]);
    gload16(sA0 + 32, &L[12288 + t * 8]);
    gload16(sA1 + 32, &L[12288 + 4096 + t * 8]);
    gload16(sB0 + 32, &L[12288 + 8192 + t * 8]);
    asm volatile("s_waitcnt vmcnt(3)" ::: "memory");
    __builtin_amdgcn_sched_barrier(0);
    __builtin_amdgcn_s_barrier();
    __builtin_amdgcn_sched_barrier(0);

    for (int kt = 0; kt < KT; ++kt) {
        const bool pre = (kt + 2) < KT;
        if (pre) {
            ushort* bp2 = &L[((kt + 2) % 3) * 12288];
            const int ko = (kt + 2) << 5;
            gload16(sA0 + ko, bp2 + t * 8);
            gload16(sA1 + ko, bp2 + 4096 + t * 8);
            gload16(sB0 + ko, bp2 + 8192 + t * 8);
        }
        const ushort* bp = &L[(kt % 3) * 12288];
        bf16x8 af[4], bw[4];
        #pragma unroll
        for (int mi = 0; mi < 4; mi++) af[mi] = *(const bf16x8*)(bp + offA[mi]);
        #pragma unroll
        for (int ni = 0; ni < 4; ni++) bw[ni] = *(const bf16x8*)(bp + offB[ni]);
        __builtin_amdgcn_s_setprio(1);
        #pragma unroll
        for (int mi = 0; mi < 4; mi++)
            #pragma unroll
            for (int ni = 0; ni < 4; ni++)
                acc[mi][ni] = __builtin_amdgcn_mfma_f32_16x16x32_bf16(af[mi], bw[ni], acc[mi][ni], 0, 0, 0);
        __builtin_amdgcn_s_setprio(0);
        if (pre) { asm volatile("s_waitcnt vmcnt(3)" ::: "memory"); }
        else     { asm volatile("s_waitcnt vmcnt(0)" ::: "memory"); }
        __builtin_amdgcn_sched_barrier(0);
        __builtin_amdgcn_s_barrier();
        __builtin_amdgcn_sched_barrier(0);
    }

    #pragma unroll
    for (int mi = 0; mi < 4; mi++)
        #pragma unroll
        for (int ni = 0; ni < 4; ni++)
            #pragma unroll
            for (int rr = 0; rr < 4; rr++) {
                const int row = row0 + wr * 64 + mi * 16 + l4 * 4 + rr;
                const int col = col0 + wc * 64 + ni * 16 + l15;
                C0[(size_t)row * ldc + col] = acc[mi][ni][rr];
            }
}

// ---------------- dt head + dA table ----------------
__global__ __launch_bounds__(256) void dt_kernel(const float* __restrict__ DBC,
                                                 const float* __restrict__ W_dt,
                                                 const float* __restrict__ dt_bias,
                                                 const float* __restrict__ A_log,
                                                 float* __restrict__ dt,
                                                 float* __restrict__ dA) {
    int idx = blockIdx.x * blockDim.x + threadIdx.x;   // t*NH + h
    int h = idx % NH;
    int tr = idx / NH;
    const float* row = DBC + (size_t)tr * 320;
    float acc = dt_bias[h];
    #pragma unroll
    for (int r = 0; r < DTRANK; r++) acc = fmaf(row[r], W_dt[h * DTRANK + r], acc);
    float sp = acc > 20.f ? acc : log1pf(expf(acc));
    sp = fminf(fmaxf(sp, 1e-4f), 1.0f);
    dt[idx] = sp;
    #pragma unroll
    for (int n = 0; n < DSTATE; n++)
        dA[(size_t)idx * DSTATE + n] = expf(sp * (-expf(A_log[h * DSTATE + n])));
}

// ---------------- scan phase 1: fused conv + per-chunk local end-state ----------------
__global__ __launch_bounds__(256) void scan_local(const ushort* __restrict__ Ub,
                                                  const float* __restrict__ DBC,
                                                  const float* __restrict__ dt_,
                                                  const float* __restrict__ dA_,
                                                  const float* __restrict__ cw,
                                                  const float* __restrict__ cb,
                                                  float* __restrict__ hloc,
                                                  float* __restrict__ Pc) {
    const int c = blockIdx.x, h = blockIdx.y;
    const int pidx = threadIdx.x;
    const int ch = h * PH + pidx;
    const int t0 = c * LC;
    __shared__ float sdA[LC][DSTATE];
    __shared__ float sdB[LC][DSTATE];
    const int st = pidx >> 4, sn = pidx & 15;
    #pragma unroll
    for (int j = 0; j < 4; j++) {
        int tt = st + j * 16;
        size_t trow = (size_t)(t0 + tt);
        float dv = dt_[trow * NH + h];
        sdA[tt][sn] = dA_[(trow * NH + h) * DSTATE + sn];
        sdB[tt][sn] = dv * DBC[trow * 320 + 64 + h * DSTATE + sn];
    }
    const float w0 = cw[ch * 4], w1 = cw[ch * 4 + 1], w2 = cw[ch * 4 + 2], w3 = cw[ch * 4 + 3];
    const float bia = cb[ch];
    const int bs = (c / NCB) * MB_ROWS;
    float um3 = (t0 - 3 >= bs) ? bf2f(Ub[(size_t)(t0 - 3) * DINNER + ch]) : 0.f;
    float um2 = (t0 - 2 >= bs) ? bf2f(Ub[(size_t)(t0 - 2) * DINNER + ch]) : 0.f;
    float um1 = (t0 - 1 >= bs) ? bf2f(Ub[(size_t)(t0 - 1) * DINNER + ch]) : 0.f;
    __syncthreads();

    float hst[DSTATE] = {};
    for (int t = 0; t < LC; t++) {
        float u0 = bf2f(Ub[(size_t)(t0 + t) * DINNER + ch]);
        float up = fmaf(w3, u0, fmaf(w2, um1, fmaf(w1, um2, fmaf(w0, um3, bia))));
        um3 = um2; um2 = um1; um1 = u0;
        #pragma unroll
        for (int n = 0; n < DSTATE; n++)
            hst[n] = fmaf(hst[n], sdA[t][n], up * sdB[t][n]);
    }
    float* hl = hloc + (((size_t)c * NH + h) * PH + pidx) * DSTATE;
    #pragma unroll
    for (int n = 0; n < DSTATE; n++) hl[n] = hst[n];

    if (pidx < DSTATE) {
        float pr = 1.f;
        for (int t = 0; t < LC; t++) pr *= sdA[t][pidx];
        Pc[((size_t)c * NH + h) * DSTATE + pidx] = pr;
    }
}

// ---------------- scan phase 2: serial carry across chunks (per batch) ----------------
__global__ __launch_bounds__(256) void scan_carry(const float* __restrict__ hloc,
                                                  const float* __restrict__ Pc,
                                                  float* __restrict__ Hent) {
    int g = blockIdx.x * 256 + threadIdx.x;
    int b = g >> 15;
    int r = g & 32767;
    int h = r >> 12;
    int inner = r & 4095;
    int n = r & 15;
    float carry = 0.f;
    for (int i = 0; i < NCB; i++) {
        int c = b * NCB + i;
        size_t idx = ((size_t)c * NH + h) * (PH * DSTATE) + inner;
        Hent[idx] = carry;
        carry = fmaf(Pc[((size_t)c * NH + h) * DSTATE + n], carry, hloc[idx]);
    }
}

// ---------------- scan phase 3: conv + re-run chunk + skip + silu gate + residual -> bf16 ----------------
__global__ __launch_bounds__(256) void scan_out(const ushort* __restrict__ Zb,
                                                const ushort* __restrict__ Ub,
                                                const ushort* __restrict__ RESb,
                                                ushort* __restrict__ Yb,
                                                const float* __restrict__ DBC,
                                                const float* __restrict__ dt_,
                                                const float* __restrict__ dA_,
                                                const float* __restrict__ cw,
                                                const float* __restrict__ cb,
                                                const float* __restrict__ Dskip,
                                                const float* __restrict__ Hent) {
    const int c = blockIdx.x, h = blockIdx.y;
    const int pidx = threadIdx.x;
    const int ch = h * PH + pidx;
    const int t0 = c * LC;
    __shared__ float sdA[LC][DSTATE];
    __shared__ float sdB[LC][DSTATE];
    __shared__ float sC [LC][DSTATE];
    const int st = pidx >> 4, sn = pidx & 15;
    #pragma unroll
    for (int j = 0; j < 4; j++) {
        int tt = st + j * 16;
        size_t trow = (size_t)(t0 + tt);
        float dv = dt_[trow * NH + h];
        sdA[tt][sn] = dA_[(trow * NH + h) * DSTATE + sn];
        sdB[tt][sn] = dv * DBC[trow * 320 + 64 + h * DSTATE + sn];
        sC [tt][sn] =      DBC[trow * 320 + 192 + h * DSTATE + sn];
    }
    const float w0 = cw[ch * 4], w1 = cw[ch * 4 + 1], w2 = cw[ch * 4 + 2], w3 = cw[ch * 4 + 3];
    const float bia = cb[ch];
    const int bs = (c / NCB) * MB_ROWS;
    float um3 = (t0 - 3 >= bs) ? bf2f(Ub[(size_t)(t0 - 3) * DINNER + ch]) : 0.f;
    float um2 = (t0 - 2 >= bs) ? bf2f(Ub[(size_t)(t0 - 2) * DINNER + ch]) : 0.f;
    float um1 = (t0 - 1 >= bs) ? bf2f(Ub[(size_t)(t0 - 1) * DINNER + ch]) : 0.f;
    const float dsk = Dskip[ch];
    float hst[DSTATE];
    const float* he = Hent + (((size_t)c * NH + h) * PH + pidx) * DSTATE;
    #pragma unroll
    for (int n = 0; n < DSTATE; n++) hst[n] = he[n];
    __syncthreads();

    for (int t = 0; t < LC; t++) {
        size_t off = (size_t)(t0 + t) * DINNER + ch;
        float u0 = bf2f(Ub[off]);
        float up = fmaf(w3, u0, fmaf(w2, um1, fmaf(w1, um2, fmaf(w0, um3, bia))));
        um3 = um2; um2 = um1; um1 = u0;
        float a0 = 0.f, a1 = 0.f, a2 = 0.f, a3 = 0.f;
        #pragma unroll
        for (int n = 0; n < 4; n++) {
            hst[n +  0] = fmaf(hst[n +  0], sdA[t][n +  0], up * sdB[t][n +  0]);
            hst[n +  4] = fmaf(hst[n +  4], sdA[t][n +  4], up * sdB[t][n +  4]);
            hst[n +  8] = fmaf(hst[n +  8], sdA[t][n +  8], up * sdB[t][n +  8]);
            hst[n + 12] = fmaf(hst[n + 12], sdA[t][n + 12], up * sdB[t][n + 12]);
            a0 = fmaf(hst[n +  0], sC[t][n +  0], a0);
            a1 = fmaf(hst[n +  4], sC[t][n +  4], a1);
            a2 = fmaf(hst[n +  8], sC[t][n +  8], a2);
            a3 = fmaf(hst[n + 12], sC[t][n + 12], a3);
        }
        float yv = ((a0 + a1) + (a2 + a3)) + dsk * up;
        float zv = bf2f(Zb[off]);
        float sil = zv / (1.f + expf(-zv));
        Yb[off] = f2bf(fmaf(yv, sil, bf2f(RESb[off])));
    }
}

// ---------------- RMSNorm (bf16 in), bf16 output ----------------
__global__ __launch_bounds__(256) void rmsnorm_bf(const ushort* __restrict__ Yb,
                                                  const float* __restrict__ norm_w,
                                                  ushort* __restrict__ Gb) {
    const int row = blockIdx.x;
    const ushort* r = Yb + (size_t)row * DINNER;
    const int c0 = threadIdx.x * 8;
    uint4 packed = *(const uint4*)(r + c0);
    float v[8];
    v[0] = bf2f((ushort)(packed.x & 0xffff)); v[1] = bf2f((ushort)(packed.x >> 16));
    v[2] = bf2f((ushort)(packed.y & 0xffff)); v[3] = bf2f((ushort)(packed.y >> 16));
    v[4] = bf2f((ushort)(packed.z & 0xffff)); v[5] = bf2f((ushort)(packed.z >> 16));
    v[6] = bf2f((ushort)(packed.w & 0xffff)); v[7] = bf2f((ushort)(packed.w >> 16));
    float ss = 0.f;
    #pragma unroll
    for (int i = 0; i < 8; i++) ss = fmaf(v[i], v[i], ss);
    #pragma unroll
    for (int off = 32; off > 0; off >>= 1) ss += __shfl_down(ss, off);
    __shared__ float red[4];
    if ((threadIdx.x & 63) == 0) red[threadIdx.x >> 6] = ss;
    __syncthreads();
    float tot = red[0] + red[1] + red[2] + red[3];
    float inv = rsqrtf(tot / (float)DINNER + 1e-6f);
    float4 w0 = *(const float4*)(norm_w + c0);
    float4 w1 = *(const float4*)(norm_w + c0 + 4);
    uint4 o;
    o.x = cvt2bf(v[0] * inv * w0.x, v[1] * inv * w0.y);
    o.y = cvt2bf(v[2] * inv * w0.z, v[3] * inv * w0.w);
    o.z = cvt2bf(v[4] * inv * w1.x, v[5] * inv * w1.y);
    o.w = cvt2bf(v[6] * inv * w1.z, v[7] * inv * w1.w);
    *(uint4*)(Gb + (size_t)row * DINNER + c0) = o;
}

// ---------------- workspace layout ----------------
struct Lay {
    float *DBC, *DT, *DA, *PC, *HLOC, *HENT;
    ushort *YB, *ZB, *UB, *RESB, *XBF, *WB;
    size_t total;
};
static Lay mk_layout(char* base, int Mr) {
    size_t o = 0;
    auto take = [&](size_t bytes) { char* p = base + o; o = (o + bytes + 255) & ~(size_t)255; return p; };
    Lay l;
    l.YB   = (ushort*)take((size_t)Mr * 2048 * 2);
    l.DBC  = (float*) take((size_t)Mr * 320 * 4);
    l.DT   = (float*) take((size_t)Mr * 8 * 4);
    l.DA   = (float*) take((size_t)Mr * 128 * 4);
    l.PC   = (float*) take((size_t)(Mr / 64) * NH * DSTATE * 4);
    l.HLOC = (float*) take((size_t)Mr * 512 * 4);
    l.HENT = (float*) take((size_t)Mr * 512 * 4);
    l.ZB   = (ushort*)take((size_t)Mr * 2048 * 2);
    l.UB   = (ushort*)take((size_t)Mr * 2048 * 2);
    l.RESB = (ushort*)take((size_t)Mr * 2048 * 2);
    l.XBF  = (ushort*)take((size_t)8192 * 1024 * 2);
    l.WB   = (ushort*)take(((size_t)NTOT * 1024 + (size_t)1024 * 2048) * 2);
    l.total = o;
    return l;
}

extern "C" void kernel_launch(void* const* d_in, const int* in_sizes, int n_in,
                              void* d_out, int out_size, void* d_ws, size_t ws_size,
                              hipStream_t stream) {
    const float* x       = (const float*)d_in[0];
    const float* W_in    = (const float*)d_in[1];
    const float* W_dt    = (const float*)d_in[2];
    const float* conv_w  = (const float*)d_in[3];
    const float* conv_b  = (const float*)d_in[4];
    const float* A_log   = (const float*)d_in[5];
    const float* Dskip   = (const float*)d_in[6];
    const float* dt_bias = (const float*)d_in[7];
    const float* norm_w  = (const float*)d_in[8];
    const float* W_out   = (const float*)d_in[9];
    const float* W_res   = (const float*)d_in[10];
    float* out = (float*)d_out;

    Lay probe = mk_layout(nullptr, 2 * MB_ROWS);
    const bool fat = ws_size >= probe.total;
    const int Mr = fat ? 2 * MB_ROWS : MB_ROWS;
    const int npass = fat ? 1 : 2;
    const int nbc = fat ? 2 : 1;
    Lay l = mk_layout((char*)d_ws, Mr);

    ushort* wcat = l.WB;                                  // [W_in|pad|W_res] NTOT x 1024
    ushort* wotb = wcat + (size_t)NTOT * 1024;            // W_out 1024 x 2048
    ushort* Gb   = l.ZB;                                  // Z dead after scan_out; reuse for g

    cvt_weights<<<((NTOT * 1024 + 2048 * 1024) / 8) / 256, 256, 0, stream>>>(W_in, W_res, W_out, l.WB);
    cvt_bf<<<(2 * MB_ROWS * DMODEL / 8) / 256, 256, 0, stream>>>(x, l.XBF);

    for (int b = 0; b < npass; b++) {
        const ushort* xb = l.XBF + (size_t)b * MB_ROWS * DMODEL;
        float* outb = out + (size_t)b * MB_ROWS * DMODEL;
        const int nty = Mr / 256;

        // 1. fused in-proj + residual GEMM -> Zb | Ub | DBC | RESb   (Mr x 6656 x 1024)
        gemm_big8<<<26 * nty, 512, 0, stream>>>(xb, wcat, l.ZB, l.UB, l.DBC, l.RESB, 26, DMODEL);
        // 2. dt head + dA table
        dt_kernel<<<(Mr * NH) / 256, 256, 0, stream>>>(l.DBC, W_dt, dt_bias, A_log, l.DT, l.DA);
        // 3. chunk-parallel scan with fused conv; y*silu(z)+res -> Yb (bf16)
        scan_local<<<dim3(Mr / LC, NH), 256, 0, stream>>>(l.UB, l.DBC, l.DT, l.DA, conv_w, conv_b, l.HLOC, l.PC);
        scan_carry<<<nbc * 128, 256, 0, stream>>>(l.HLOC, l.PC, l.HENT);
        scan_out<<<dim3(Mr / LC, NH), 256, 0, stream>>>(l.ZB, l.UB, l.RESB, l.YB, l.DBC, l.DT, l.DA,
                                                        conv_w, conv_b, Dskip, l.HENT);
        // 4. RMSNorm (bf16 in) -> bf16 g
        rmsnorm_bf<<<Mr, 256, 0, stream>>>(l.YB, norm_w, Gb);
        // 5. out-projection: out = g @ W_out^T (fp32 out)
        gemm_out<<<8 * nty, 512, 0, stream>>>(Gb, wotb, outb, 8, DINNER, DMODEL);
    }
}

// Round 10
// 305.721 us; speedup vs baseline: 1.1017x; 1.1017x over previous
//
#include <hip/hip_runtime.h>
#include <hip/hip_bf16.h>
#include <math.h>

#define DMODEL  1024
#define DINNER  2048
#define DSTATE  16
#define DCONV   4
#define DTRANK  64
#define NH      8
#define PH      256
#define TOTOUT  4416
#define NPAD    4608            // W_in rows padded (zeros 4416..4607)
#define NTOT    6656            // [W_in 4416 | pad 192 | W_res 2048]
#define MB_ROWS 4096            // rows per batch
#define LC      64              // scan chunk length
#define NCB     (MB_ROWS/LC)    // 64 chunks per batch

typedef __attribute__((ext_vector_type(8))) short bf16x8;
typedef __attribute__((ext_vector_type(4))) float f32x4;

__device__ inline unsigned cvt2bf(float lo, float hi) {
    unsigned r;
    asm("v_cvt_pk_bf16_f32 %0, %1, %2" : "=v"(r) : "v"(lo), "v"(hi));
    return r;
}
__device__ inline ushort f2bf(float v) { return (ushort)(cvt2bf(v, v) & 0xffffu); }
__device__ inline float bf2f(ushort u) {
    union { unsigned u; float f; } w; w.u = (unsigned)u << 16; return w.f;
}
__device__ inline void gload16(const ushort* g, ushort* l) {
    __builtin_amdgcn_global_load_lds((const __attribute__((address_space(1))) unsigned*)(const void*)g,
                                     (__attribute__((address_space(3))) unsigned*)(void*)l, 16, 0, 0);
}

// ---------------- fp32 -> bf16 convert ----------------
__global__ __launch_bounds__(256) void cvt_bf(const float* __restrict__ s,
                                              ushort* __restrict__ d) {
    size_t i = ((size_t)blockIdx.x * 256 + threadIdx.x) * 8;
    float4 v0 = *(const float4*)(s + i);
    float4 v1 = *(const float4*)(s + i + 4);
    uint4 o;
    o.x = cvt2bf(v0.x, v0.y); o.y = cvt2bf(v0.z, v0.w);
    o.z = cvt2bf(v1.x, v1.y); o.w = cvt2bf(v1.z, v1.w);
    *(uint4*)(d + i) = o;
}

// ---------------- fused weight convert: [W_in | pad | W_res] (NTOT rows) + W_out ----------------
__global__ __launch_bounds__(256) void cvt_weights(const float* __restrict__ W_in,
                                                   const float* __restrict__ W_res,
                                                   const float* __restrict__ W_out,
                                                   ushort* __restrict__ dst) {
    const size_t E0 = (size_t)TOTOUT * DMODEL;
    const size_t E1 = (size_t)NPAD * DMODEL;
    const size_t E2 = (size_t)NTOT * DMODEL;
    size_t i = ((size_t)blockIdx.x * 256 + threadIdx.x) * 8;
    float4 v0, v1;
    if (i < E1) {
        if (i < E0) { v0 = *(const float4*)(W_in + i); v1 = *(const float4*)(W_in + i + 4); }
        else { v0 = make_float4(0.f,0.f,0.f,0.f); v1 = v0; }
    } else if (i < E2) {
        size_t o = i - E1; v0 = *(const float4*)(W_res + o); v1 = *(const float4*)(W_res + o + 4);
    } else {
        size_t o = i - E2; v0 = *(const float4*)(W_out + o); v1 = *(const float4*)(W_out + o + 4);
    }
    uint4 o;
    o.x = cvt2bf(v0.x, v0.y); o.y = cvt2bf(v0.z, v0.w);
    o.z = cvt2bf(v1.x, v1.y); o.w = cvt2bf(v1.z, v1.w);
    *(uint4*)(dst + i) = o;
}

// ========== fused GEMM: 256x128 tile, tri-buffer, counted vmcnt(3) (round-7 proven) ==========
// C = A[Mr x 1024]bf16 x Wcat[6656 x 1024]^T, split epilogue Zb|Ub|DBC|RESb.
// 8 waves (4M x 2N), 64x64 per wave, BK=32, 3 LDS buffers (72 KB -> 2 blocks/CU).
__global__ __launch_bounds__(512) void gemm_fused(const ushort* __restrict__ A,
                                                  const ushort* __restrict__ W,
                                                  ushort* __restrict__ Zb,
                                                  ushort* __restrict__ Ub,
                                                  float* __restrict__ DBCp,
                                                  ushort* __restrict__ RESb,
                                                  int ntx, int K) {
    __shared__ __align__(16) ushort L[3 * 12288];
    const int nwg  = gridDim.x;
    const int orig = blockIdx.x;
    const int swz  = (orig & 7) * (nwg >> 3) + (orig >> 3);   // bijective: nwg % 8 == 0
    const int bx = swz % ntx, by = swz / ntx;
    const int row0 = by * 256, col0 = bx * 128;

    const int t    = threadIdx.x;
    const int lane = t & 63, w = t >> 6;
    const int wr   = w >> 1, wc = w & 1;       // 4 M-waves x 2 N-waves
    const int l15  = lane & 15, l4 = lane >> 4;

    const int r0g = t >> 2, s0g = t & 3;
    const int r1g = r0g + 128;
    const int rr0 = r0g ^ ((r0g >> 3) & 1), cc0 = s0g ^ ((r0g >> 1) & 3);
    const int rr1 = r1g ^ ((r1g >> 3) & 1), cc1 = s0g ^ ((r1g >> 1) & 3);
    const ushort* sA0 = A + (size_t)(row0 + rr0) * K + cc0 * 8;
    const ushort* sA1 = A + (size_t)(row0 + rr1) * K + cc1 * 8;
    const ushort* sB0 = W + (size_t)(col0 + rr0) * K + cc0 * 8;

    int offA[4], offB[4];
    #pragma unroll
    for (int mi = 0; mi < 4; mi++) {
        int rq = wr * 64 + mi * 16 + l15;
        offA[mi] = (rq * 32 + l4 * 8) ^ (((rq >> 1) & 7) << 3);
    }
    #pragma unroll
    for (int ni = 0; ni < 4; ni++) {
        int rq = wc * 64 + ni * 16 + l15;
        offB[ni] = 8192 + ((rq * 32 + l4 * 8) ^ (((rq >> 1) & 7) << 3));
    }

    f32x4 acc[4][4];
    #pragma unroll
    for (int i = 0; i < 4; i++)
        #pragma unroll
        for (int j = 0; j < 4; j++)
            acc[i][j] = (f32x4){0.f, 0.f, 0.f, 0.f};

    const int KT = K >> 5;
    // prologue: T0 -> buf0, T1 -> buf1
    gload16(sA0,      &L[t * 8]);
    gload16(sA1,      &L[4096 + t * 8]);
    gload16(sB0,      &L[8192 + t * 8]);
    gload16(sA0 + 32, &L[12288 + t * 8]);
    gload16(sA1 + 32, &L[12288 + 4096 + t * 8]);
    gload16(sB0 + 32, &L[12288 + 8192 + t * 8]);
    asm volatile("s_waitcnt vmcnt(3)" ::: "memory");
    __builtin_amdgcn_sched_barrier(0);
    __builtin_amdgcn_s_barrier();
    __builtin_amdgcn_sched_barrier(0);

    for (int kt = 0; kt < KT; ++kt) {
        const bool pre = (kt + 2) < KT;
        if (pre) {
            ushort* bp2 = &L[((kt + 2) % 3) * 12288];
            const int ko = (kt + 2) << 5;
            gload16(sA0 + ko, bp2 + t * 8);
            gload16(sA1 + ko, bp2 + 4096 + t * 8);
            gload16(sB0 + ko, bp2 + 8192 + t * 8);
        }
        const ushort* bp = &L[(kt % 3) * 12288];
        bf16x8 af[4], bw[4];
        #pragma unroll
        for (int mi = 0; mi < 4; mi++) af[mi] = *(const bf16x8*)(bp + offA[mi]);
        #pragma unroll
        for (int ni = 0; ni < 4; ni++) bw[ni] = *(const bf16x8*)(bp + offB[ni]);
        __builtin_amdgcn_s_setprio(1);
        #pragma unroll
        for (int mi = 0; mi < 4; mi++)
            #pragma unroll
            for (int ni = 0; ni < 4; ni++)
                acc[mi][ni] = __builtin_amdgcn_mfma_f32_16x16x32_bf16(af[mi], bw[ni], acc[mi][ni], 0, 0, 0);
        __builtin_amdgcn_s_setprio(0);
        if (pre) { asm volatile("s_waitcnt vmcnt(3)" ::: "memory"); }
        else     { asm volatile("s_waitcnt vmcnt(0)" ::: "memory"); }
        __builtin_amdgcn_sched_barrier(0);
        __builtin_amdgcn_s_barrier();
        __builtin_amdgcn_sched_barrier(0);
    }

    // epilogue: C/D col=lane&15, row=(lane>>4)*4+reg [m89/m91]; split by col0 (block-uniform)
    #pragma unroll
    for (int mi = 0; mi < 4; mi++) {
        #pragma unroll
        for (int ni = 0; ni < 4; ni++) {
            #pragma unroll
            for (int rr = 0; rr < 4; rr++) {
                const int row = row0 + wr * 64 + mi * 16 + l4 * 4 + rr;
                const int col = col0 + wc * 64 + ni * 16 + l15;
                const float v = acc[mi][ni][rr];
                if (col0 < DINNER) {
                    Zb[(size_t)row * DINNER + col] = f2bf(v);
                } else if (col0 < 2 * DINNER) {
                    Ub[(size_t)row * DINNER + (col - DINNER)] = f2bf(v);
                } else if (col0 < NPAD) {
                    if (col < TOTOUT)
                        DBCp[(size_t)row * 320 + (col - 2 * DINNER)] = v;
                } else {
                    RESb[(size_t)row * DINNER + (col - NPAD)] = f2bf(v);
                }
            }
        }
    }
}

// ========== out-proj GEMM: 128x128 tile, tri-buffer, counted vmcnt(4), fp32 out ==========
// 4 waves (2M x 2N), 64x64 per wave, BK=32, 3 LDS buffers (48 KB -> 3 blocks/CU cap).
__global__ __launch_bounds__(256) void gemm_out128(const ushort* __restrict__ A,
                                                   const ushort* __restrict__ W,
                                                   float* __restrict__ C0,
                                                   int ntx, int K, int ldc) {
    __shared__ __align__(16) ushort L[3 * 8192];
    const int nwg  = gridDim.x;
    const int orig = blockIdx.x;
    const int swz  = (orig & 7) * (nwg >> 3) + (orig >> 3);
    const int bx = swz % ntx, by = swz / ntx;
    const int row0 = by * 128, col0 = bx * 128;

    const int t    = threadIdx.x;
    const int lane = t & 63, w = t >> 6;
    const int wr   = w >> 1, wc = w & 1;       // 2 M-waves x 2 N-waves
    const int l15  = lane & 15, l4 = lane >> 4;

    // staging: granule sets (rows 0-63) and (rows 64-127), 4 k-chunks
    const int r0g = t >> 2, s0g = t & 3;
    const int r1g = r0g + 64;
    const int rr0 = r0g ^ ((r0g >> 3) & 1), cc0 = s0g ^ ((r0g >> 1) & 3);
    const int rr1 = r1g ^ ((r1g >> 3) & 1), cc1 = s0g ^ ((r1g >> 1) & 3);
    const ushort* sA0 = A + (size_t)(row0 + rr0) * K + cc0 * 8;
    const ushort* sA1 = A + (size_t)(row0 + rr1) * K + cc1 * 8;
    const ushort* sB0 = W + (size_t)(col0 + rr0) * K + cc0 * 8;
    const ushort* sB1 = W + (size_t)(col0 + rr1) * K + cc1 * 8;

    int offA[4], offB[4];
    #pragma unroll
    for (int mi = 0; mi < 4; mi++) {
        int rq = wr * 64 + mi * 16 + l15;
        offA[mi] = (rq * 32 + l4 * 8) ^ (((rq >> 1) & 7) << 3);
    }
    #pragma unroll
    for (int ni = 0; ni < 4; ni++) {
        int rq = wc * 64 + ni * 16 + l15;
        offB[ni] = 4096 + ((rq * 32 + l4 * 8) ^ (((rq >> 1) & 7) << 3));
    }

    f32x4 acc[4][4];
    #pragma unroll
    for (int i = 0; i < 4; i++)
        #pragma unroll
        for (int j = 0; j < 4; j++)
            acc[i][j] = (f32x4){0.f, 0.f, 0.f, 0.f};

    const int KT = K >> 5;
    // prologue: T0 -> buf0, T1 -> buf1 (4 gloads per tile per thread)
    gload16(sA0,      &L[t * 8]);
    gload16(sA1,      &L[2048 + t * 8]);
    gload16(sB0,      &L[4096 + t * 8]);
    gload16(sB1,      &L[6144 + t * 8]);
    gload16(sA0 + 32, &L[8192 + t * 8]);
    gload16(sA1 + 32, &L[8192 + 2048 + t * 8]);
    gload16(sB0 + 32, &L[8192 + 4096 + t * 8]);
    gload16(sB1 + 32, &L[8192 + 6144 + t * 8]);
    asm volatile("s_waitcnt vmcnt(4)" ::: "memory");
    __builtin_amdgcn_sched_barrier(0);
    __builtin_amdgcn_s_barrier();
    __builtin_amdgcn_sched_barrier(0);

    for (int kt = 0; kt < KT; ++kt) {
        const bool pre = (kt + 2) < KT;
        if (pre) {
            ushort* bp2 = &L[((kt + 2) % 3) * 8192];
            const int ko = (kt + 2) << 5;
            gload16(sA0 + ko, bp2 + t * 8);
            gload16(sA1 + ko, bp2 + 2048 + t * 8);
            gload16(sB0 + ko, bp2 + 4096 + t * 8);
            gload16(sB1 + ko, bp2 + 6144 + t * 8);
        }
        const ushort* bp = &L[(kt % 3) * 8192];
        bf16x8 af[4], bw[4];
        #pragma unroll
        for (int mi = 0; mi < 4; mi++) af[mi] = *(const bf16x8*)(bp + offA[mi]);
        #pragma unroll
        for (int ni = 0; ni < 4; ni++) bw[ni] = *(const bf16x8*)(bp + offB[ni]);
        __builtin_amdgcn_s_setprio(1);
        #pragma unroll
        for (int mi = 0; mi < 4; mi++)
            #pragma unroll
            for (int ni = 0; ni < 4; ni++)
                acc[mi][ni] = __builtin_amdgcn_mfma_f32_16x16x32_bf16(af[mi], bw[ni], acc[mi][ni], 0, 0, 0);
        __builtin_amdgcn_s_setprio(0);
        if (pre) { asm volatile("s_waitcnt vmcnt(4)" ::: "memory"); }
        else     { asm volatile("s_waitcnt vmcnt(0)" ::: "memory"); }
        __builtin_amdgcn_sched_barrier(0);
        __builtin_amdgcn_s_barrier();
        __builtin_amdgcn_sched_barrier(0);
    }

    #pragma unroll
    for (int mi = 0; mi < 4; mi++)
        #pragma unroll
        for (int ni = 0; ni < 4; ni++)
            #pragma unroll
            for (int rr = 0; rr < 4; rr++) {
                const int row = row0 + wr * 64 + mi * 16 + l4 * 4 + rr;
                const int col = col0 + wc * 64 + ni * 16 + l15;
                C0[(size_t)row * ldc + col] = acc[mi][ni][rr];
            }
}

// ---------------- dt head + dA table ----------------
__global__ __launch_bounds__(256) void dt_kernel(const float* __restrict__ DBC,
                                                 const float* __restrict__ W_dt,
                                                 const float* __restrict__ dt_bias,
                                                 const float* __restrict__ A_log,
                                                 float* __restrict__ dt,
                                                 float* __restrict__ dA) {
    int idx = blockIdx.x * blockDim.x + threadIdx.x;   // t*NH + h
    int h = idx % NH;
    int tr = idx / NH;
    const float* row = DBC + (size_t)tr * 320;
    float acc = dt_bias[h];
    #pragma unroll
    for (int r = 0; r < DTRANK; r++) acc = fmaf(row[r], W_dt[h * DTRANK + r], acc);
    float sp = acc > 20.f ? acc : log1pf(expf(acc));
    sp = fminf(fmaxf(sp, 1e-4f), 1.0f);
    dt[idx] = sp;
    #pragma unroll
    for (int n = 0; n < DSTATE; n++)
        dA[(size_t)idx * DSTATE + n] = expf(sp * (-expf(A_log[h * DSTATE + n])));
}

// ---------------- scan phase 1: fused conv + per-chunk local end-state ----------------
__global__ __launch_bounds__(256) void scan_local(const ushort* __restrict__ Ub,
                                                  const float* __restrict__ DBC,
                                                  const float* __restrict__ dt_,
                                                  const float* __restrict__ dA_,
                                                  const float* __restrict__ cw,
                                                  const float* __restrict__ cb,
                                                  float* __restrict__ hloc,
                                                  float* __restrict__ Pc) {
    const int c = blockIdx.x, h = blockIdx.y;
    const int pidx = threadIdx.x;
    const int ch = h * PH + pidx;
    const int t0 = c * LC;
    __shared__ float sdA[LC][DSTATE];
    __shared__ float sdB[LC][DSTATE];
    const int st = pidx >> 4, sn = pidx & 15;
    #pragma unroll
    for (int j = 0; j < 4; j++) {
        int tt = st + j * 16;
        size_t trow = (size_t)(t0 + tt);
        float dv = dt_[trow * NH + h];
        sdA[tt][sn] = dA_[(trow * NH + h) * DSTATE + sn];
        sdB[tt][sn] = dv * DBC[trow * 320 + 64 + h * DSTATE + sn];
    }
    const float w0 = cw[ch * 4], w1 = cw[ch * 4 + 1], w2 = cw[ch * 4 + 2], w3 = cw[ch * 4 + 3];
    const float bia = cb[ch];
    const int bs = (c / NCB) * MB_ROWS;
    float um3 = (t0 - 3 >= bs) ? bf2f(Ub[(size_t)(t0 - 3) * DINNER + ch]) : 0.f;
    float um2 = (t0 - 2 >= bs) ? bf2f(Ub[(size_t)(t0 - 2) * DINNER + ch]) : 0.f;
    float um1 = (t0 - 1 >= bs) ? bf2f(Ub[(size_t)(t0 - 1) * DINNER + ch]) : 0.f;
    __syncthreads();

    float hst[DSTATE] = {};
    for (int t = 0; t < LC; t++) {
        float u0 = bf2f(Ub[(size_t)(t0 + t) * DINNER + ch]);
        float up = fmaf(w3, u0, fmaf(w2, um1, fmaf(w1, um2, fmaf(w0, um3, bia))));
        um3 = um2; um2 = um1; um1 = u0;
        #pragma unroll
        for (int n = 0; n < DSTATE; n++)
            hst[n] = fmaf(hst[n], sdA[t][n], up * sdB[t][n]);
    }
    float* hl = hloc + (((size_t)c * NH + h) * PH + pidx) * DSTATE;
    #pragma unroll
    for (int n = 0; n < DSTATE; n++) hl[n] = hst[n];

    if (pidx < DSTATE) {
        float pr = 1.f;
        for (int t = 0; t < LC; t++) pr *= sdA[t][pidx];
        Pc[((size_t)c * NH + h) * DSTATE + pidx] = pr;
    }
}

// ---------------- scan phase 2: serial carry across chunks (per batch) ----------------
__global__ __launch_bounds__(256) void scan_carry(const float* __restrict__ hloc,
                                                  const float* __restrict__ Pc,
                                                  float* __restrict__ Hent) {
    int g = blockIdx.x * 256 + threadIdx.x;
    int b = g >> 15;
    int r = g & 32767;
    int h = r >> 12;
    int inner = r & 4095;
    int n = r & 15;
    float carry = 0.f;
    for (int i = 0; i < NCB; i++) {
        int c = b * NCB + i;
        size_t idx = ((size_t)c * NH + h) * (PH * DSTATE) + inner;
        Hent[idx] = carry;
        carry = fmaf(Pc[((size_t)c * NH + h) * DSTATE + n], carry, hloc[idx]);
    }
}

// ---------------- scan phase 3: conv + re-run chunk + skip + silu gate + residual -> bf16 ----------------
__global__ __launch_bounds__(256) void scan_out(const ushort* __restrict__ Zb,
                                                const ushort* __restrict__ Ub,
                                                const ushort* __restrict__ RESb,
                                                ushort* __restrict__ Yb,
                                                const float* __restrict__ DBC,
                                                const float* __restrict__ dt_,
                                                const float* __restrict__ dA_,
                                                const float* __restrict__ cw,
                                                const float* __restrict__ cb,
                                                const float* __restrict__ Dskip,
                                                const float* __restrict__ Hent) {
    const int c = blockIdx.x, h = blockIdx.y;
    const int pidx = threadIdx.x;
    const int ch = h * PH + pidx;
    const int t0 = c * LC;
    __shared__ float sdA[LC][DSTATE];
    __shared__ float sdB[LC][DSTATE];
    __shared__ float sC [LC][DSTATE];
    const int st = pidx >> 4, sn = pidx & 15;
    #pragma unroll
    for (int j = 0; j < 4; j++) {
        int tt = st + j * 16;
        size_t trow = (size_t)(t0 + tt);
        float dv = dt_[trow * NH + h];
        sdA[tt][sn] = dA_[(trow * NH + h) * DSTATE + sn];
        sdB[tt][sn] = dv * DBC[trow * 320 + 64 + h * DSTATE + sn];
        sC [tt][sn] =      DBC[trow * 320 + 192 + h * DSTATE + sn];
    }
    const float w0 = cw[ch * 4], w1 = cw[ch * 4 + 1], w2 = cw[ch * 4 + 2], w3 = cw[ch * 4 + 3];
    const float bia = cb[ch];
    const int bs = (c / NCB) * MB_ROWS;
    float um3 = (t0 - 3 >= bs) ? bf2f(Ub[(size_t)(t0 - 3) * DINNER + ch]) : 0.f;
    float um2 = (t0 - 2 >= bs) ? bf2f(Ub[(size_t)(t0 - 2) * DINNER + ch]) : 0.f;
    float um1 = (t0 - 1 >= bs) ? bf2f(Ub[(size_t)(t0 - 1) * DINNER + ch]) : 0.f;
    const float dsk = Dskip[ch];
    float hst[DSTATE];
    const float* he = Hent + (((size_t)c * NH + h) * PH + pidx) * DSTATE;
    #pragma unroll
    for (int n = 0; n < DSTATE; n++) hst[n] = he[n];
    __syncthreads();

    for (int t = 0; t < LC; t++) {
        size_t off = (size_t)(t0 + t) * DINNER + ch;
        float u0 = bf2f(Ub[off]);
        float up = fmaf(w3, u0, fmaf(w2, um1, fmaf(w1, um2, fmaf(w0, um3, bia))));
        um3 = um2; um2 = um1; um1 = u0;
        float a0 = 0.f, a1 = 0.f, a2 = 0.f, a3 = 0.f;
        #pragma unroll
        for (int n = 0; n < 4; n++) {
            hst[n +  0] = fmaf(hst[n +  0], sdA[t][n +  0], up * sdB[t][n +  0]);
            hst[n +  4] = fmaf(hst[n +  4], sdA[t][n +  4], up * sdB[t][n +  4]);
            hst[n +  8] = fmaf(hst[n +  8], sdA[t][n +  8], up * sdB[t][n +  8]);
            hst[n + 12] = fmaf(hst[n + 12], sdA[t][n + 12], up * sdB[t][n + 12]);
            a0 = fmaf(hst[n +  0], sC[t][n +  0], a0);
            a1 = fmaf(hst[n +  4], sC[t][n +  4], a1);
            a2 = fmaf(hst[n +  8], sC[t][n +  8], a2);
            a3 = fmaf(hst[n + 12], sC[t][n + 12], a3);
        }
        float yv = ((a0 + a1) + (a2 + a3)) + dsk * up;
        float zv = bf2f(Zb[off]);
        float sil = zv / (1.f + expf(-zv));
        Yb[off] = f2bf(fmaf(yv, sil, bf2f(RESb[off])));
    }
}

// ---------------- RMSNorm (bf16 in), bf16 output ----------------
__global__ __launch_bounds__(256) void rmsnorm_bf(const ushort* __restrict__ Yb,
                                                  const float* __restrict__ norm_w,
                                                  ushort* __restrict__ Gb) {
    const int row = blockIdx.x;
    const ushort* r = Yb + (size_t)row * DINNER;
    const int c0 = threadIdx.x * 8;
    uint4 packed = *(const uint4*)(r + c0);
    float v[8];
    v[0] = bf2f((ushort)(packed.x & 0xffff)); v[1] = bf2f((ushort)(packed.x >> 16));
    v[2] = bf2f((ushort)(packed.y & 0xffff)); v[3] = bf2f((ushort)(packed.y >> 16));
    v[4] = bf2f((ushort)(packed.z & 0xffff)); v[5] = bf2f((ushort)(packed.z >> 16));
    v[6] = bf2f((ushort)(packed.w & 0xffff)); v[7] = bf2f((ushort)(packed.w >> 16));
    float ss = 0.f;
    #pragma unroll
    for (int i = 0; i < 8; i++) ss = fmaf(v[i], v[i], ss);
    #pragma unroll
    for (int off = 32; off > 0; off >>= 1) ss += __shfl_down(ss, off);
    __shared__ float red[4];
    if ((threadIdx.x & 63) == 0) red[threadIdx.x >> 6] = ss;
    __syncthreads();
    float tot = red[0] + red[1] + red[2] + red[3];
    float inv = rsqrtf(tot / (float)DINNER + 1e-6f);
    float4 w0 = *(const float4*)(norm_w + c0);
    float4 w1 = *(const float4*)(norm_w + c0 + 4);
    uint4 o;
    o.x = cvt2bf(v[0] * inv * w0.x, v[1] * inv * w0.y);
    o.y = cvt2bf(v[2] * inv * w0.z, v[3] * inv * w0.w);
    o.z = cvt2bf(v[4] * inv * w1.x, v[5] * inv * w1.y);
    o.w = cvt2bf(v[6] * inv * w1.z, v[7] * inv * w1.w);
    *(uint4*)(Gb + (size_t)row * DINNER + c0) = o;
}

// ---------------- workspace layout ----------------
struct Lay {
    float *DBC, *DT, *DA, *PC, *HLOC, *HENT;
    ushort *YB, *ZB, *UB, *RESB, *XBF, *WB;
    size_t total;
};
static Lay mk_layout(char* base, int Mr) {
    size_t o = 0;
    auto take = [&](size_t bytes) { char* p = base + o; o = (o + bytes + 255) & ~(size_t)255; return p; };
    Lay l;
    l.YB   = (ushort*)take((size_t)Mr * 2048 * 2);
    l.DBC  = (float*) take((size_t)Mr * 320 * 4);
    l.DT   = (float*) take((size_t)Mr * 8 * 4);
    l.DA   = (float*) take((size_t)Mr * 128 * 4);
    l.PC   = (float*) take((size_t)(Mr / 64) * NH * DSTATE * 4);
    l.HLOC = (float*) take((size_t)Mr * 512 * 4);
    l.HENT = (float*) take((size_t)Mr * 512 * 4);
    l.ZB   = (ushort*)take((size_t)Mr * 2048 * 2);
    l.UB   = (ushort*)take((size_t)Mr * 2048 * 2);
    l.RESB = (ushort*)take((size_t)Mr * 2048 * 2);
    l.XBF  = (ushort*)take((size_t)8192 * 1024 * 2);
    l.WB   = (ushort*)take(((size_t)NTOT * 1024 + (size_t)1024 * 2048) * 2);
    l.total = o;
    return l;
}

extern "C" void kernel_launch(void* const* d_in, const int* in_sizes, int n_in,
                              void* d_out, int out_size, void* d_ws, size_t ws_size,
                              hipStream_t stream) {
    const float* x       = (const float*)d_in[0];
    const float* W_in    = (const float*)d_in[1];
    const float* W_dt    = (const float*)d_in[2];
    const float* conv_w  = (const float*)d_in[3];
    const float* conv_b  = (const float*)d_in[4];
    const float* A_log   = (const float*)d_in[5];
    const float* Dskip   = (const float*)d_in[6];
    const float* dt_bias = (const float*)d_in[7];
    const float* norm_w  = (const float*)d_in[8];
    const float* W_out   = (const float*)d_in[9];
    const float* W_res   = (const float*)d_in[10];
    float* out = (float*)d_out;

    Lay probe = mk_layout(nullptr, 2 * MB_ROWS);
    const bool fat = ws_size >= probe.total;
    const int Mr = fat ? 2 * MB_ROWS : MB_ROWS;
    const int npass = fat ? 1 : 2;
    const int nbc = fat ? 2 : 1;
    Lay l = mk_layout((char*)d_ws, Mr);

    ushort* wcat = l.WB;                                  // [W_in|pad|W_res] NTOT x 1024
    ushort* wotb = wcat + (size_t)NTOT * 1024;            // W_out 1024 x 2048
    ushort* Gb   = l.ZB;                                  // Z dead after scan_out; reuse for g

    cvt_weights<<<((NTOT * 1024 + 2048 * 1024) / 8) / 256, 256, 0, stream>>>(W_in, W_res, W_out, l.WB);
    cvt_bf<<<(2 * MB_ROWS * DMODEL / 8) / 256, 256, 0, stream>>>(x, l.XBF);

    for (int b = 0; b < npass; b++) {
        const ushort* xb = l.XBF + (size_t)b * MB_ROWS * DMODEL;
        float* outb = out + (size_t)b * MB_ROWS * DMODEL;

        // 1. fused in-proj + residual GEMM -> Zb | Ub | DBC | RESb   (Mr x 6656 x 1024)
        gemm_fused<<<52 * (Mr / 256), 512, 0, stream>>>(xb, wcat, l.ZB, l.UB, l.DBC, l.RESB, 52, DMODEL);
        // 2. dt head + dA table
        dt_kernel<<<(Mr * NH) / 256, 256, 0, stream>>>(l.DBC, W_dt, dt_bias, A_log, l.DT, l.DA);
        // 3. chunk-parallel scan with fused conv; y*silu(z)+res -> Yb (bf16)
        scan_local<<<dim3(Mr / LC, NH), 256, 0, stream>>>(l.UB, l.DBC, l.DT, l.DA, conv_w, conv_b, l.HLOC, l.PC);
        scan_carry<<<nbc * 128, 256, 0, stream>>>(l.HLOC, l.PC, l.HENT);
        scan_out<<<dim3(Mr / LC, NH), 256, 0, stream>>>(l.ZB, l.UB, l.RESB, l.YB, l.DBC, l.DT, l.DA,
                                                        conv_w, conv_b, Dskip, l.HENT);
        // 4. RMSNorm (bf16 in) -> bf16 g
        rmsnorm_bf<<<Mr, 256, 0, stream>>>(l.YB, norm_w, Gb);
        // 5. out-projection: out = g @ W_out^T (fp32 out), 128x128 tiles
        gemm_out128<<<8 * (Mr / 128), 256, 0, stream>>>(Gb, wotb, outb, 8, DINNER, DMODEL);
    }
}

// Round 11
// 300.559 us; speedup vs baseline: 1.1206x; 1.0172x over previous
//
#include <hip/hip_runtime.h>
#include <hip/hip_bf16.h>
#include <math.h>

#define DMODEL  1024
#define DINNER  2048
#define DSTATE  16
#define DCONV   4
#define DTRANK  64
#define NH      8
#define PH      256
#define TOTOUT  4416
#define NTOT2   6528            // [Z 2048 | U 2048 | RES 2048 | DBC 320+64pad] = 51*128
#define MB_ROWS 4096            // rows per batch
#define LC      64              // scan chunk length
#define NCB     (MB_ROWS/LC)    // 64 chunks per batch

typedef __attribute__((ext_vector_type(8))) short bf16x8;
typedef __attribute__((ext_vector_type(4))) float f32x4;

__device__ inline unsigned cvt2bf(float lo, float hi) {
    unsigned r;
    asm("v_cvt_pk_bf16_f32 %0, %1, %2" : "=v"(r) : "v"(lo), "v"(hi));
    return r;
}
__device__ inline ushort f2bf(float v) { return (ushort)(cvt2bf(v, v) & 0xffffu); }
__device__ inline float bf2f(ushort u) {
    union { unsigned u; float f; } w; w.u = (unsigned)u << 16; return w.f;
}
__device__ inline void gload16(const ushort* g, ushort* l) {
    __builtin_amdgcn_global_load_lds((const __attribute__((address_space(1))) unsigned*)(const void*)g,
                                     (__attribute__((address_space(3))) unsigned*)(void*)l, 16, 0, 0);
}

// ---------------- fused convert: Wcat repack [Wz|Wu|Wres|Wbc|pad] + W_out + x ----------------
__global__ __launch_bounds__(256) void cvt_all(const float* __restrict__ W_in,
                                               const float* __restrict__ W_res,
                                               const float* __restrict__ W_out,
                                               const float* __restrict__ x,
                                               ushort* __restrict__ WB,
                                               ushort* __restrict__ XBF) {
    const size_t E_WCAT = (size_t)NTOT2 * DMODEL;                 // 6,684,672
    const size_t E_WOUT = E_WCAT + (size_t)DMODEL * DINNER;       // + 2,097,152
    size_t i = ((size_t)blockIdx.x * 256 + threadIdx.x) * 8;
    const float* src;
    ushort* dst;
    bool zero = false;
    if (i < E_WCAT) {
        size_t r = i >> 10, c = i & 1023;
        if (r < 4096)       src = W_in + (r << 10) + c;           // z,u rows
        else if (r < 6144)  src = W_res + ((r - 4096) << 10) + c; // res rows
        else if (r < 6464)  src = W_in + ((r - 2048) << 10) + c;  // dbc rows 4096..4415
        else { src = W_in; zero = true; }                          // pad rows
        dst = WB + i;
    } else if (i < E_WOUT) {
        src = W_out + (i - E_WCAT);
        dst = WB + i;
    } else {
        src = x + (i - E_WOUT);
        dst = XBF + (i - E_WOUT);
    }
    float4 v0, v1;
    if (zero) { v0 = make_float4(0.f, 0.f, 0.f, 0.f); v1 = v0; }
    else { v0 = *(const float4*)src; v1 = *(const float4*)(src + 4); }
    uint4 o;
    o.x = cvt2bf(v0.x, v0.y); o.y = cvt2bf(v0.z, v0.w);
    o.z = cvt2bf(v1.x, v1.y); o.w = cvt2bf(v1.z, v1.w);
    *(uint4*)dst = o;
}

// ========== fused GEMM: 256x128 tile, tri-buffer, counted vmcnt(3) ==========
// C = A[Mr x 1024]bf16 x Wcat[6528 x 1024]^T, split epilogue Zb|Ub|RESb|DBC.
// 8 waves (4M x 2N), 64x64/wave, BK=32, 72 KB LDS -> 2 blocks/CU.
// EXPERIMENT: extra s_barrier between frag ds_reads and MFMA cluster (load/MFMA window split).
__global__ __launch_bounds__(512) void gemm_fused(const ushort* __restrict__ A,
                                                  const ushort* __restrict__ W,
                                                  ushort* __restrict__ Zb,
                                                  ushort* __restrict__ Ub,
                                                  ushort* __restrict__ RESb,
                                                  float* __restrict__ DBCp,
                                                  int ntx, int K) {
    __shared__ __align__(16) ushort L[3 * 12288];
    const int nwg  = gridDim.x;
    const int orig = blockIdx.x;
    const int swz  = (orig & 7) * (nwg >> 3) + (orig >> 3);   // bijective: nwg % 8 == 0
    const int bx = swz % ntx, by = swz / ntx;
    const int row0 = by * 256, col0 = bx * 128;

    const int t    = threadIdx.x;
    const int lane = t & 63, w = t >> 6;
    const int wr   = w >> 1, wc = w & 1;       // 4 M-waves x 2 N-waves
    const int l15  = lane & 15, l4 = lane >> 4;

    const int r0g = t >> 2, s0g = t & 3;
    const int r1g = r0g + 128;
    const int rr0 = r0g ^ ((r0g >> 3) & 1), cc0 = s0g ^ ((r0g >> 1) & 3);
    const int rr1 = r1g ^ ((r1g >> 3) & 1), cc1 = s0g ^ ((r1g >> 1) & 3);
    const ushort* sA0 = A + (size_t)(row0 + rr0) * K + cc0 * 8;
    const ushort* sA1 = A + (size_t)(row0 + rr1) * K + cc1 * 8;
    const ushort* sB0 = W + (size_t)(col0 + rr0) * K + cc0 * 8;

    int offA[4], offB[4];
    #pragma unroll
    for (int mi = 0; mi < 4; mi++) {
        int rq = wr * 64 + mi * 16 + l15;
        offA[mi] = (rq * 32 + l4 * 8) ^ (((rq >> 1) & 7) << 3);
    }
    #pragma unroll
    for (int ni = 0; ni < 4; ni++) {
        int rq = wc * 64 + ni * 16 + l15;
        offB[ni] = 8192 + ((rq * 32 + l4 * 8) ^ (((rq >> 1) & 7) << 3));
    }

    f32x4 acc[4][4];
    #pragma unroll
    for (int i = 0; i < 4; i++)
        #pragma unroll
        for (int j = 0; j < 4; j++)
            acc[i][j] = (f32x4){0.f, 0.f, 0.f, 0.f};

    const int KT = K >> 5;
    gload16(sA0,      &L[t * 8]);
    gload16(sA1,      &L[4096 + t * 8]);
    gload16(sB0,      &L[8192 + t * 8]);
    gload16(sA0 + 32, &L[12288 + t * 8]);
    gload16(sA1 + 32, &L[12288 + 4096 + t * 8]);
    gload16(sB0 + 32, &L[12288 + 8192 + t * 8]);
    asm volatile("s_waitcnt vmcnt(3)" ::: "memory");
    __builtin_amdgcn_sched_barrier(0);
    __builtin_amdgcn_s_barrier();
    __builtin_amdgcn_sched_barrier(0);

    for (int kt = 0; kt < KT; ++kt) {
        const bool pre = (kt + 2) < KT;
        if (pre) {
            ushort* bp2 = &L[((kt + 2) % 3) * 12288];
            const int ko = (kt + 2) << 5;
            gload16(sA0 + ko, bp2 + t * 8);
            gload16(sA1 + ko, bp2 + 4096 + t * 8);
            gload16(sB0 + ko, bp2 + 8192 + t * 8);
        }
        const ushort* bp = &L[(kt % 3) * 12288];
        bf16x8 af[4], bw[4];
        #pragma unroll
        for (int mi = 0; mi < 4; mi++) af[mi] = *(const bf16x8*)(bp + offA[mi]);
        #pragma unroll
        for (int ni = 0; ni < 4; ni++) bw[ni] = *(const bf16x8*)(bp + offB[ni]);
        // ---- load-window / MFMA-window split (experiment) ----
        __builtin_amdgcn_sched_barrier(0);
        __builtin_amdgcn_s_barrier();
        __builtin_amdgcn_sched_barrier(0);
        __builtin_amdgcn_s_setprio(1);
        #pragma unroll
        for (int mi = 0; mi < 4; mi++)
            #pragma unroll
            for (int ni = 0; ni < 4; ni++)
                acc[mi][ni] = __builtin_amdgcn_mfma_f32_16x16x32_bf16(af[mi], bw[ni], acc[mi][ni], 0, 0, 0);
        __builtin_amdgcn_s_setprio(0);
        if (pre) { asm volatile("s_waitcnt vmcnt(3)" ::: "memory"); }
        else     { asm volatile("s_waitcnt vmcnt(0)" ::: "memory"); }
        __builtin_amdgcn_sched_barrier(0);
        __builtin_amdgcn_s_barrier();
        __builtin_amdgcn_sched_barrier(0);
    }

    // epilogue: C/D col=lane&15, row=(lane>>4)*4+reg [m89/m91]; split by col0 (block-uniform)
    #pragma unroll
    for (int mi = 0; mi < 4; mi++) {
        #pragma unroll
        for (int ni = 0; ni < 4; ni++) {
            #pragma unroll
            for (int rr = 0; rr < 4; rr++) {
                const int row = row0 + wr * 64 + mi * 16 + l4 * 4 + rr;
                const int col = col0 + wc * 64 + ni * 16 + l15;
                const float v = acc[mi][ni][rr];
                if (col0 < DINNER) {
                    Zb[(size_t)row * DINNER + col] = f2bf(v);
                } else if (col0 < 2 * DINNER) {
                    Ub[(size_t)row * DINNER + (col - DINNER)] = f2bf(v);
                } else if (col0 < 3 * DINNER) {
                    RESb[(size_t)row * DINNER + (col - 2 * DINNER)] = f2bf(v);
                } else {
                    if (col < 3 * DINNER + 320)
                        DBCp[(size_t)row * 320 + (col - 3 * DINNER)] = v;
                }
            }
        }
    }
}

// ========== out-proj GEMM: 128x128 tile, tri-buffer, counted vmcnt(4), fp32 out (control) ==========
__global__ __launch_bounds__(256) void gemm_out128(const ushort* __restrict__ A,
                                                   const ushort* __restrict__ W,
                                                   float* __restrict__ C0,
                                                   int ntx, int K, int ldc) {
    __shared__ __align__(16) ushort L[3 * 8192];
    const int nwg  = gridDim.x;
    const int orig = blockIdx.x;
    const int swz  = (orig & 7) * (nwg >> 3) + (orig >> 3);
    const int bx = swz % ntx, by = swz / ntx;
    const int row0 = by * 128, col0 = bx * 128;

    const int t    = threadIdx.x;
    const int lane = t & 63, w = t >> 6;
    const int wr   = w >> 1, wc = w & 1;
    const int l15  = lane & 15, l4 = lane >> 4;

    const int r0g = t >> 2, s0g = t & 3;
    const int r1g = r0g + 64;
    const int rr0 = r0g ^ ((r0g >> 3) & 1), cc0 = s0g ^ ((r0g >> 1) & 3);
    const int rr1 = r1g ^ ((r1g >> 3) & 1), cc1 = s0g ^ ((r1g >> 1) & 3);
    const ushort* sA0 = A + (size_t)(row0 + rr0) * K + cc0 * 8;
    const ushort* sA1 = A + (size_t)(row0 + rr1) * K + cc1 * 8;
    const ushort* sB0 = W + (size_t)(col0 + rr0) * K + cc0 * 8;
    const ushort* sB1 = W + (size_t)(col0 + rr1) * K + cc1 * 8;

    int offA[4], offB[4];
    #pragma unroll
    for (int mi = 0; mi < 4; mi++) {
        int rq = wr * 64 + mi * 16 + l15;
        offA[mi] = (rq * 32 + l4 * 8) ^ (((rq >> 1) & 7) << 3);
    }
    #pragma unroll
    for (int ni = 0; ni < 4; ni++) {
        int rq = wc * 64 + ni * 16 + l15;
        offB[ni] = 4096 + ((rq * 32 + l4 * 8) ^ (((rq >> 1) & 7) << 3));
    }

    f32x4 acc[4][4];
    #pragma unroll
    for (int i = 0; i < 4; i++)
        #pragma unroll
        for (int j = 0; j < 4; j++)
            acc[i][j] = (f32x4){0.f, 0.f, 0.f, 0.f};

    const int KT = K >> 5;
    gload16(sA0,      &L[t * 8]);
    gload16(sA1,      &L[2048 + t * 8]);
    gload16(sB0,      &L[4096 + t * 8]);
    gload16(sB1,      &L[6144 + t * 8]);
    gload16(sA0 + 32, &L[8192 + t * 8]);
    gload16(sA1 + 32, &L[8192 + 2048 + t * 8]);
    gload16(sB0 + 32, &L[8192 + 4096 + t * 8]);
    gload16(sB1 + 32, &L[8192 + 6144 + t * 8]);
    asm volatile("s_waitcnt vmcnt(4)" ::: "memory");
    __builtin_amdgcn_sched_barrier(0);
    __builtin_amdgcn_s_barrier();
    __builtin_amdgcn_sched_barrier(0);

    for (int kt = 0; kt < KT; ++kt) {
        const bool pre = (kt + 2) < KT;
        if (pre) {
            ushort* bp2 = &L[((kt + 2) % 3) * 8192];
            const int ko = (kt + 2) << 5;
            gload16(sA0 + ko, bp2 + t * 8);
            gload16(sA1 + ko, bp2 + 2048 + t * 8);
            gload16(sB0 + ko, bp2 + 4096 + t * 8);
            gload16(sB1 + ko, bp2 + 6144 + t * 8);
        }
        const ushort* bp = &L[(kt % 3) * 8192];
        bf16x8 af[4], bw[4];
        #pragma unroll
        for (int mi = 0; mi < 4; mi++) af[mi] = *(const bf16x8*)(bp + offA[mi]);
        #pragma unroll
        for (int ni = 0; ni < 4; ni++) bw[ni] = *(const bf16x8*)(bp + offB[ni]);
        __builtin_amdgcn_s_setprio(1);
        #pragma unroll
        for (int mi = 0; mi < 4; mi++)
            #pragma unroll
            for (int ni = 0; ni < 4; ni++)
                acc[mi][ni] = __builtin_amdgcn_mfma_f32_16x16x32_bf16(af[mi], bw[ni], acc[mi][ni], 0, 0, 0);
        __builtin_amdgcn_s_setprio(0);
        if (pre) { asm volatile("s_waitcnt vmcnt(4)" ::: "memory"); }
        else     { asm volatile("s_waitcnt vmcnt(0)" ::: "memory"); }
        __builtin_amdgcn_sched_barrier(0);
        __builtin_amdgcn_s_barrier();
        __builtin_amdgcn_sched_barrier(0);
    }

    #pragma unroll
    for (int mi = 0; mi < 4; mi++)
        #pragma unroll
        for (int ni = 0; ni < 4; ni++)
            #pragma unroll
            for (int rr = 0; rr < 4; rr++) {
                const int row = row0 + wr * 64 + mi * 16 + l4 * 4 + rr;
                const int col = col0 + wc * 64 + ni * 16 + l15;
                C0[(size_t)row * ldc + col] = acc[mi][ni][rr];
            }
}

// ---------------- scan phase 1: inline dt + fused conv + per-chunk local end-state ----------------
__global__ __launch_bounds__(256) void scan_local(const ushort* __restrict__ Ub,
                                                  const float* __restrict__ DBC,
                                                  const float* __restrict__ W_dt,
                                                  const float* __restrict__ dt_bias,
                                                  const float* __restrict__ A_log,
                                                  const float* __restrict__ cw,
                                                  const float* __restrict__ cb,
                                                  float* __restrict__ hloc,
                                                  float* __restrict__ Pc) {
    const int c = blockIdx.x, h = blockIdx.y;
    const int pidx = threadIdx.x;
    const int ch = h * PH + pidx;
    const int t0 = c * LC;
    __shared__ float sdt[LC];
    __shared__ float sdA[LC][DSTATE];
    __shared__ float sdB[LC][DSTATE];
    const int st = pidx >> 4, sn = pidx & 15;

    if (pidx < LC) {   // dt head: dot64 + softplus + clip
        const float* row = DBC + (size_t)(t0 + pidx) * 320;
        const float* wd = W_dt + h * DTRANK;
        float acc = dt_bias[h];
        #pragma unroll 16
        for (int r2 = 0; r2 < DTRANK; r2++) acc = fmaf(row[r2], wd[r2], acc);
        float sp = acc > 20.f ? acc : log1pf(expf(acc));
        sdt[pidx] = fminf(fmaxf(sp, 1e-4f), 1.0f);
    }
    const float w0 = cw[ch * 4], w1 = cw[ch * 4 + 1], w2 = cw[ch * 4 + 2], w3 = cw[ch * 4 + 3];
    const float bia = cb[ch];
    const int bs = (c / NCB) * MB_ROWS;
    float um3 = (t0 - 3 >= bs) ? bf2f(Ub[(size_t)(t0 - 3) * DINNER + ch]) : 0.f;
    float um2 = (t0 - 2 >= bs) ? bf2f(Ub[(size_t)(t0 - 2) * DINNER + ch]) : 0.f;
    float um1 = (t0 - 1 >= bs) ? bf2f(Ub[(size_t)(t0 - 1) * DINNER + ch]) : 0.f;
    __syncthreads();

    {   // coefficient staging with inline dA = exp(dt * -exp(A_log))
        const float nA = -expf(A_log[h * DSTATE + sn]);
        #pragma unroll
        for (int j = 0; j < 4; j++) {
            int tt = st + j * 16;
            size_t trow = (size_t)(t0 + tt);
            float dv = sdt[tt];
            sdA[tt][sn] = expf(dv * nA);
            sdB[tt][sn] = dv * DBC[trow * 320 + 64 + h * DSTATE + sn];
        }
    }
    __syncthreads();

    float hst[DSTATE] = {};
    for (int t = 0; t < LC; t++) {
        float u0 = bf2f(Ub[(size_t)(t0 + t) * DINNER + ch]);
        float up = fmaf(w3, u0, fmaf(w2, um1, fmaf(w1, um2, fmaf(w0, um3, bia))));
        um3 = um2; um2 = um1; um1 = u0;
        #pragma unroll
        for (int n = 0; n < DSTATE; n++)
            hst[n] = fmaf(hst[n], sdA[t][n], up * sdB[t][n]);
    }
    float* hl = hloc + (((size_t)c * NH + h) * PH + pidx) * DSTATE;
    #pragma unroll
    for (int n = 0; n < DSTATE; n++) hl[n] = hst[n];

    if (pidx < DSTATE) {
        float pr = 1.f;
        for (int t = 0; t < LC; t++) pr *= sdA[t][pidx];
        Pc[((size_t)c * NH + h) * DSTATE + pidx] = pr;
    }
}

// ---------------- scan phase 2: serial carry across chunks (per batch) ----------------
__global__ __launch_bounds__(256) void scan_carry(const float* __restrict__ hloc,
                                                  const float* __restrict__ Pc,
                                                  float* __restrict__ Hent) {
    int g = blockIdx.x * 256 + threadIdx.x;
    int b = g >> 15;
    int r = g & 32767;
    int h = r >> 12;
    int inner = r & 4095;
    int n = r & 15;
    float carry = 0.f;
    for (int i = 0; i < NCB; i++) {
        int c = b * NCB + i;
        size_t idx = ((size_t)c * NH + h) * (PH * DSTATE) + inner;
        Hent[idx] = carry;
        carry = fmaf(Pc[((size_t)c * NH + h) * DSTATE + n], carry, hloc[idx]);
    }
}

// ---------------- scan phase 3: inline dt + conv + re-run chunk + skip + silu gate + residual ----------------
__global__ __launch_bounds__(256) void scan_out(const ushort* __restrict__ Zb,
                                                const ushort* __restrict__ Ub,
                                                const ushort* __restrict__ RESb,
                                                ushort* __restrict__ Yb,
                                                const float* __restrict__ DBC,
                                                const float* __restrict__ W_dt,
                                                const float* __restrict__ dt_bias,
                                                const float* __restrict__ A_log,
                                                const float* __restrict__ cw,
                                                const float* __restrict__ cb,
                                                const float* __restrict__ Dskip,
                                                const float* __restrict__ Hent) {
    const int c = blockIdx.x, h = blockIdx.y;
    const int pidx = threadIdx.x;
    const int ch = h * PH + pidx;
    const int t0 = c * LC;
    __shared__ float sdt[LC];
    __shared__ float sdA[LC][DSTATE];
    __shared__ float sdB[LC][DSTATE];
    __shared__ float sC [LC][DSTATE];
    const int st = pidx >> 4, sn = pidx & 15;

    if (pidx < LC) {
        const float* row = DBC + (size_t)(t0 + pidx) * 320;
        const float* wd = W_dt + h * DTRANK;
        float acc = dt_bias[h];
        #pragma unroll 16
        for (int r2 = 0; r2 < DTRANK; r2++) acc = fmaf(row[r2], wd[r2], acc);
        float sp = acc > 20.f ? acc : log1pf(expf(acc));
        sdt[pidx] = fminf(fmaxf(sp, 1e-4f), 1.0f);
    }
    const float w0 = cw[ch * 4], w1 = cw[ch * 4 + 1], w2 = cw[ch * 4 + 2], w3 = cw[ch * 4 + 3];
    const float bia = cb[ch];
    const int bs = (c / NCB) * MB_ROWS;
    float um3 = (t0 - 3 >= bs) ? bf2f(Ub[(size_t)(t0 - 3) * DINNER + ch]) : 0.f;
    float um2 = (t0 - 2 >= bs) ? bf2f(Ub[(size_t)(t0 - 2) * DINNER + ch]) : 0.f;
    float um1 = (t0 - 1 >= bs) ? bf2f(Ub[(size_t)(t0 - 1) * DINNER + ch]) : 0.f;
    __syncthreads();

    {
        const float nA = -expf(A_log[h * DSTATE + sn]);
        #pragma unroll
        for (int j = 0; j < 4; j++) {
            int tt = st + j * 16;
            size_t trow = (size_t)(t0 + tt);
            float dv = sdt[tt];
            sdA[tt][sn] = expf(dv * nA);
            sdB[tt][sn] = dv * DBC[trow * 320 + 64 + h * DSTATE + sn];
            sC [tt][sn] =      DBC[trow * 320 + 192 + h * DSTATE + sn];
        }
    }
    const float dsk = Dskip[ch];
    float hst[DSTATE];
    const float* he = Hent + (((size_t)c * NH + h) * PH + pidx) * DSTATE;
    #pragma unroll
    for (int n = 0; n < DSTATE; n++) hst[n] = he[n];
    __syncthreads();

    for (int t = 0; t < LC; t++) {
        size_t off = (size_t)(t0 + t) * DINNER + ch;
        float u0 = bf2f(Ub[off]);
        float up = fmaf(w3, u0, fmaf(w2, um1, fmaf(w1, um2, fmaf(w0, um3, bia))));
        um3 = um2; um2 = um1; um1 = u0;
        float a0 = 0.f, a1 = 0.f, a2 = 0.f, a3 = 0.f;
        #pragma unroll
        for (int n = 0; n < 4; n++) {
            hst[n +  0] = fmaf(hst[n +  0], sdA[t][n +  0], up * sdB[t][n +  0]);
            hst[n +  4] = fmaf(hst[n +  4], sdA[t][n +  4], up * sdB[t][n +  4]);
            hst[n +  8] = fmaf(hst[n +  8], sdA[t][n +  8], up * sdB[t][n +  8]);
            hst[n + 12] = fmaf(hst[n + 12], sdA[t][n + 12], up * sdB[t][n + 12]);
            a0 = fmaf(hst[n +  0], sC[t][n +  0], a0);
            a1 = fmaf(hst[n +  4], sC[t][n +  4], a1);
            a2 = fmaf(hst[n +  8], sC[t][n +  8], a2);
            a3 = fmaf(hst[n + 12], sC[t][n + 12], a3);
        }
        float yv = ((a0 + a1) + (a2 + a3)) + dsk * up;
        float zv = bf2f(Zb[off]);
        float sil = zv / (1.f + expf(-zv));
        Yb[off] = f2bf(fmaf(yv, sil, bf2f(RESb[off])));
    }
}

// ---------------- RMSNorm (bf16 in), bf16 output ----------------
__global__ __launch_bounds__(256) void rmsnorm_bf(const ushort* __restrict__ Yb,
                                                  const float* __restrict__ norm_w,
                                                  ushort* __restrict__ Gb) {
    const int row = blockIdx.x;
    const ushort* r = Yb + (size_t)row * DINNER;
    const int c0 = threadIdx.x * 8;
    uint4 packed = *(const uint4*)(r + c0);
    float v[8];
    v[0] = bf2f((ushort)(packed.x & 0xffff)); v[1] = bf2f((ushort)(packed.x >> 16));
    v[2] = bf2f((ushort)(packed.y & 0xffff)); v[3] = bf2f((ushort)(packed.y >> 16));
    v[4] = bf2f((ushort)(packed.z & 0xffff)); v[5] = bf2f((ushort)(packed.z >> 16));
    v[6] = bf2f((ushort)(packed.w & 0xffff)); v[7] = bf2f((ushort)(packed.w >> 16));
    float ss = 0.f;
    #pragma unroll
    for (int i = 0; i < 8; i++) ss = fmaf(v[i], v[i], ss);
    #pragma unroll
    for (int off = 32; off > 0; off >>= 1) ss += __shfl_down(ss, off);
    __shared__ float red[4];
    if ((threadIdx.x & 63) == 0) red[threadIdx.x >> 6] = ss;
    __syncthreads();
    float tot = red[0] + red[1] + red[2] + red[3];
    float inv = rsqrtf(tot / (float)DINNER + 1e-6f);
    float4 w0 = *(const float4*)(norm_w + c0);
    float4 w1 = *(const float4*)(norm_w + c0 + 4);
    uint4 o;
    o.x = cvt2bf(v[0] * inv * w0.x, v[1] * inv * w0.y);
    o.y = cvt2bf(v[2] * inv * w0.z, v[3] * inv * w0.w);
    o.z = cvt2bf(v[4] * inv * w1.x, v[5] * inv * w1.y);
    o.w = cvt2bf(v[6] * inv * w1.z, v[7] * inv * w1.w);
    *(uint4*)(Gb + (size_t)row * DINNER + c0) = o;
}

// ---------------- workspace layout ----------------
struct Lay {
    float *DBC, *PC, *HLOC, *HENT;
    ushort *YB, *ZB, *UB, *RESB, *XBF, *WB;
    size_t total;
};
static Lay mk_layout(char* base, int Mr) {
    size_t o = 0;
    auto take = [&](size_t bytes) { char* p = base + o; o = (o + bytes + 255) & ~(size_t)255; return p; };
    Lay l;
    l.YB   = (ushort*)take((size_t)Mr * 2048 * 2);
    l.DBC  = (float*) take((size_t)Mr * 320 * 4);
    l.PC   = (float*) take((size_t)(Mr / 64) * NH * DSTATE * 4);
    l.HLOC = (float*) take((size_t)Mr * 512 * 4);
    l.HENT = (float*) take((size_t)Mr * 512 * 4);
    l.ZB   = (ushort*)take((size_t)Mr * 2048 * 2);
    l.UB   = (ushort*)take((size_t)Mr * 2048 * 2);
    l.RESB = (ushort*)take((size_t)Mr * 2048 * 2);
    l.XBF  = (ushort*)take((size_t)8192 * 1024 * 2);
    l.WB   = (ushort*)take(((size_t)NTOT2 * 1024 + (size_t)1024 * 2048) * 2);
    l.total = o;
    return l;
}

extern "C" void kernel_launch(void* const* d_in, const int* in_sizes, int n_in,
                              void* d_out, int out_size, void* d_ws, size_t ws_size,
                              hipStream_t stream) {
    const float* x       = (const float*)d_in[0];
    const float* W_in    = (const float*)d_in[1];
    const float* W_dt    = (const float*)d_in[2];
    const float* conv_w  = (const float*)d_in[3];
    const float* conv_b  = (const float*)d_in[4];
    const float* A_log   = (const float*)d_in[5];
    const float* Dskip   = (const float*)d_in[6];
    const float* dt_bias = (const float*)d_in[7];
    const float* norm_w  = (const float*)d_in[8];
    const float* W_out   = (const float*)d_in[9];
    const float* W_res   = (const float*)d_in[10];
    float* out = (float*)d_out;

    Lay probe = mk_layout(nullptr, 2 * MB_ROWS);
    const bool fat = ws_size >= probe.total;
    const int Mr = fat ? 2 * MB_ROWS : MB_ROWS;
    const int npass = fat ? 1 : 2;
    const int nbc = fat ? 2 : 1;
    Lay l = mk_layout((char*)d_ws, Mr);

    ushort* wcat = l.WB;                                  // repacked [Z|U|RES|DBC] 6528 x 1024
    ushort* wotb = wcat + (size_t)NTOT2 * 1024;           // W_out 1024 x 2048
    ushort* Gb   = l.ZB;                                  // Z dead after scan_out; reuse for g

    // one fused conversion: weights (repacked) + W_out + x
    {
        const size_t total_gran = ((size_t)NTOT2 * 1024 + (size_t)1024 * 2048 + (size_t)8192 * 1024) / 8;
        cvt_all<<<(int)(total_gran / 256), 256, 0, stream>>>(W_in, W_res, W_out, x, l.WB, l.XBF);
    }

    for (int b = 0; b < npass; b++) {
        const ushort* xb = l.XBF + (size_t)b * MB_ROWS * DMODEL;
        float* outb = out + (size_t)b * MB_ROWS * DMODEL;

        // 1. fused in-proj + residual GEMM -> Zb | Ub | RESb | DBC   (Mr x 6528 x 1024)
        gemm_fused<<<51 * (Mr / 256), 512, 0, stream>>>(xb, wcat, l.ZB, l.UB, l.RESB, l.DBC, 51, DMODEL);
        // 2. chunk-parallel scan (inline dt, fused conv); y*silu(z)+res -> Yb (bf16)
        scan_local<<<dim3(Mr / LC, NH), 256, 0, stream>>>(l.UB, l.DBC, W_dt, dt_bias, A_log,
                                                          conv_w, conv_b, l.HLOC, l.PC);
        scan_carry<<<nbc * 128, 256, 0, stream>>>(l.HLOC, l.PC, l.HENT);
        scan_out<<<dim3(Mr / LC, NH), 256, 0, stream>>>(l.ZB, l.UB, l.RESB, l.YB, l.DBC,
                                                        W_dt, dt_bias, A_log,
                                                        conv_w, conv_b, Dskip, l.HENT);
        // 3. RMSNorm (bf16 in) -> bf16 g
        rmsnorm_bf<<<Mr, 256, 0, stream>>>(l.YB, norm_w, Gb);
        // 4. out-projection: out = g @ W_out^T (fp32 out), 128x128 tiles
        gemm_out128<<<8 * (Mr / 128), 256, 0, stream>>>(Gb, wotb, outb, 8, DINNER, DMODEL);
    }
}

// Round 12
// 297.173 us; speedup vs baseline: 1.1333x; 1.0114x over previous
//
#include <hip/hip_runtime.h>
#include <hip/hip_bf16.h>
#include <math.h>

#define DMODEL  1024
#define DINNER  2048
#define DSTATE  16
#define DCONV   4
#define DTRANK  64
#define NH      8
#define PH      256
#define TOTOUT  4416
#define NTOT2   6528            // [Z 2048 | U 2048 | RES 2048 | DBC 320+64pad] = 51*128
#define MB_ROWS 4096            // rows per batch
#define LC      64              // scan chunk length
#define NCB     (MB_ROWS/LC)    // 64 chunks per batch

typedef __attribute__((ext_vector_type(8))) short bf16x8;
typedef __attribute__((ext_vector_type(4))) float f32x4;

__device__ inline unsigned cvt2bf(float lo, float hi) {
    unsigned r;
    asm("v_cvt_pk_bf16_f32 %0, %1, %2" : "=v"(r) : "v"(lo), "v"(hi));
    return r;
}
__device__ inline ushort f2bf(float v) { return (ushort)(cvt2bf(v, v) & 0xffffu); }
__device__ inline float bf2f(ushort u) {
    union { unsigned u; float f; } w; w.u = (unsigned)u << 16; return w.f;
}
__device__ inline void gload16(const ushort* g, ushort* l) {
    __builtin_amdgcn_global_load_lds((const __attribute__((address_space(1))) unsigned*)(const void*)g,
                                     (__attribute__((address_space(3))) unsigned*)(void*)l, 16, 0, 0);
}

// ---------------- fused convert: Wcat repack [Wz|Wu|Wres|Wbc|pad] + W_out + x ----------------
__global__ __launch_bounds__(256) void cvt_all(const float* __restrict__ W_in,
                                               const float* __restrict__ W_res,
                                               const float* __restrict__ W_out,
                                               const float* __restrict__ x,
                                               ushort* __restrict__ WB,
                                               ushort* __restrict__ XBF) {
    const size_t E_WCAT = (size_t)NTOT2 * DMODEL;
    const size_t E_WOUT = E_WCAT + (size_t)DMODEL * DINNER;
    size_t i = ((size_t)blockIdx.x * 256 + threadIdx.x) * 8;
    const float* src;
    ushort* dst;
    bool zero = false;
    if (i < E_WCAT) {
        size_t r = i >> 10, c = i & 1023;
        if (r < 4096)       src = W_in + (r << 10) + c;           // z,u rows
        else if (r < 6144)  src = W_res + ((r - 4096) << 10) + c; // res rows
        else if (r < 6464)  src = W_in + ((r - 2048) << 10) + c;  // dbc rows 4096..4415
        else { src = W_in; zero = true; }                          // pad rows
        dst = WB + i;
    } else if (i < E_WOUT) {
        src = W_out + (i - E_WCAT);
        dst = WB + i;
    } else {
        src = x + (i - E_WOUT);
        dst = XBF + (i - E_WOUT);
    }
    float4 v0, v1;
    if (zero) { v0 = make_float4(0.f, 0.f, 0.f, 0.f); v1 = v0; }
    else { v0 = *(const float4*)src; v1 = *(const float4*)(src + 4); }
    uint4 o;
    o.x = cvt2bf(v0.x, v0.y); o.y = cvt2bf(v0.z, v0.w);
    o.z = cvt2bf(v1.x, v1.y); o.w = cvt2bf(v1.z, v1.w);
    *(uint4*)dst = o;
}

// ========== fused GEMM: 256x128 tile, tri-buffer, counted vmcnt(3) (round-10 proven) ==========
// C = A[Mr x 1024]bf16 x Wcat[6528 x 1024]^T, split epilogue Zb|Ub|RESb|DBC.
// 8 waves (4M x 2N), 64x64/wave, BK=32, 72 KB LDS -> 2 blocks/CU.
__global__ __launch_bounds__(512) void gemm_fused(const ushort* __restrict__ A,
                                                  const ushort* __restrict__ W,
                                                  ushort* __restrict__ Zb,
                                                  ushort* __restrict__ Ub,
                                                  ushort* __restrict__ RESb,
                                                  float* __restrict__ DBCp,
                                                  int ntx, int K) {
    __shared__ __align__(16) ushort L[3 * 12288];
    const int nwg  = gridDim.x;
    const int orig = blockIdx.x;
    const int swz  = (orig & 7) * (nwg >> 3) + (orig >> 3);   // bijective: nwg % 8 == 0
    const int bx = swz % ntx, by = swz / ntx;
    const int row0 = by * 256, col0 = bx * 128;

    const int t    = threadIdx.x;
    const int lane = t & 63, w = t >> 6;
    const int wr   = w >> 1, wc = w & 1;       // 4 M-waves x 2 N-waves
    const int l15  = lane & 15, l4 = lane >> 4;

    const int r0g = t >> 2, s0g = t & 3;
    const int r1g = r0g + 128;
    const int rr0 = r0g ^ ((r0g >> 3) & 1), cc0 = s0g ^ ((r0g >> 1) & 3);
    const int rr1 = r1g ^ ((r1g >> 3) & 1), cc1 = s0g ^ ((r1g >> 1) & 3);
    const ushort* sA0 = A + (size_t)(row0 + rr0) * K + cc0 * 8;
    const ushort* sA1 = A + (size_t)(row0 + rr1) * K + cc1 * 8;
    const ushort* sB0 = W + (size_t)(col0 + rr0) * K + cc0 * 8;

    int offA[4], offB[4];
    #pragma unroll
    for (int mi = 0; mi < 4; mi++) {
        int rq = wr * 64 + mi * 16 + l15;
        offA[mi] = (rq * 32 + l4 * 8) ^ (((rq >> 1) & 7) << 3);
    }
    #pragma unroll
    for (int ni = 0; ni < 4; ni++) {
        int rq = wc * 64 + ni * 16 + l15;
        offB[ni] = 8192 + ((rq * 32 + l4 * 8) ^ (((rq >> 1) & 7) << 3));
    }

    f32x4 acc[4][4];
    #pragma unroll
    for (int i = 0; i < 4; i++)
        #pragma unroll
        for (int j = 0; j < 4; j++)
            acc[i][j] = (f32x4){0.f, 0.f, 0.f, 0.f};

    const int KT = K >> 5;
    gload16(sA0,      &L[t * 8]);
    gload16(sA1,      &L[4096 + t * 8]);
    gload16(sB0,      &L[8192 + t * 8]);
    gload16(sA0 + 32, &L[12288 + t * 8]);
    gload16(sA1 + 32, &L[12288 + 4096 + t * 8]);
    gload16(sB0 + 32, &L[12288 + 8192 + t * 8]);
    asm volatile("s_waitcnt vmcnt(3)" ::: "memory");
    __builtin_amdgcn_sched_barrier(0);
    __builtin_amdgcn_s_barrier();
    __builtin_amdgcn_sched_barrier(0);

    for (int kt = 0; kt < KT; ++kt) {
        const bool pre = (kt + 2) < KT;
        if (pre) {
            ushort* bp2 = &L[((kt + 2) % 3) * 12288];
            const int ko = (kt + 2) << 5;
            gload16(sA0 + ko, bp2 + t * 8);
            gload16(sA1 + ko, bp2 + 4096 + t * 8);
            gload16(sB0 + ko, bp2 + 8192 + t * 8);
        }
        const ushort* bp = &L[(kt % 3) * 12288];
        bf16x8 af[4], bw[4];
        #pragma unroll
        for (int mi = 0; mi < 4; mi++) af[mi] = *(const bf16x8*)(bp + offA[mi]);
        #pragma unroll
        for (int ni = 0; ni < 4; ni++) bw[ni] = *(const bf16x8*)(bp + offB[ni]);
        __builtin_amdgcn_s_setprio(1);
        #pragma unroll
        for (int mi = 0; mi < 4; mi++)
            #pragma unroll
            for (int ni = 0; ni < 4; ni++)
                acc[mi][ni] = __builtin_amdgcn_mfma_f32_16x16x32_bf16(af[mi], bw[ni], acc[mi][ni], 0, 0, 0);
        __builtin_amdgcn_s_setprio(0);
        if (pre) { asm volatile("s_waitcnt vmcnt(3)" ::: "memory"); }
        else     { asm volatile("s_waitcnt vmcnt(0)" ::: "memory"); }
        __builtin_amdgcn_sched_barrier(0);
        __builtin_amdgcn_s_barrier();
        __builtin_amdgcn_sched_barrier(0);
    }

    // epilogue: C/D col=lane&15, row=(lane>>4)*4+reg [m89/m91]; split by col0 (block-uniform)
    #pragma unroll
    for (int mi = 0; mi < 4; mi++) {
        #pragma unroll
        for (int ni = 0; ni < 4; ni++) {
            #pragma unroll
            for (int rr = 0; rr < 4; rr++) {
                const int row = row0 + wr * 64 + mi * 16 + l4 * 4 + rr;
                const int col = col0 + wc * 64 + ni * 16 + l15;
                const float v = acc[mi][ni][rr];
                if (col0 < DINNER) {
                    Zb[(size_t)row * DINNER + col] = f2bf(v);
                } else if (col0 < 2 * DINNER) {
                    Ub[(size_t)row * DINNER + (col - DINNER)] = f2bf(v);
                } else if (col0 < 3 * DINNER) {
                    RESb[(size_t)row * DINNER + (col - 2 * DINNER)] = f2bf(v);
                } else {
                    if (col < 3 * DINNER + 320)
                        DBCp[(size_t)row * 320 + (col - 3 * DINNER)] = v;
                }
            }
        }
    }
}

// ========== out-proj GEMM: 128x128 tile, tri-buffer, counted vmcnt(4), fp32 out ==========
__global__ __launch_bounds__(256) void gemm_out128(const ushort* __restrict__ A,
                                                   const ushort* __restrict__ W,
                                                   float* __restrict__ C0,
                                                   int ntx, int K, int ldc) {
    __shared__ __align__(16) ushort L[3 * 8192];
    const int nwg  = gridDim.x;
    const int orig = blockIdx.x;
    const int swz  = (orig & 7) * (nwg >> 3) + (orig >> 3);
    const int bx = swz % ntx, by = swz / ntx;
    const int row0 = by * 128, col0 = bx * 128;

    const int t    = threadIdx.x;
    const int lane = t & 63, w = t >> 6;
    const int wr   = w >> 1, wc = w & 1;
    const int l15  = lane & 15, l4 = lane >> 4;

    const int r0g = t >> 2, s0g = t & 3;
    const int r1g = r0g + 64;
    const int rr0 = r0g ^ ((r0g >> 3) & 1), cc0 = s0g ^ ((r0g >> 1) & 3);
    const int rr1 = r1g ^ ((r1g >> 3) & 1), cc1 = s0g ^ ((r1g >> 1) & 3);
    const ushort* sA0 = A + (size_t)(row0 + rr0) * K + cc0 * 8;
    const ushort* sA1 = A + (size_t)(row0 + rr1) * K + cc1 * 8;
    const ushort* sB0 = W + (size_t)(col0 + rr0) * K + cc0 * 8;
    const ushort* sB1 = W + (size_t)(col0 + rr1) * K + cc1 * 8;

    int offA[4], offB[4];
    #pragma unroll
    for (int mi = 0; mi < 4; mi++) {
        int rq = wr * 64 + mi * 16 + l15;
        offA[mi] = (rq * 32 + l4 * 8) ^ (((rq >> 1) & 7) << 3);
    }
    #pragma unroll
    for (int ni = 0; ni < 4; ni++) {
        int rq = wc * 64 + ni * 16 + l15;
        offB[ni] = 4096 + ((rq * 32 + l4 * 8) ^ (((rq >> 1) & 7) << 3));
    }

    f32x4 acc[4][4];
    #pragma unroll
    for (int i = 0; i < 4; i++)
        #pragma unroll
        for (int j = 0; j < 4; j++)
            acc[i][j] = (f32x4){0.f, 0.f, 0.f, 0.f};

    const int KT = K >> 5;
    gload16(sA0,      &L[t * 8]);
    gload16(sA1,      &L[2048 + t * 8]);
    gload16(sB0,      &L[4096 + t * 8]);
    gload16(sB1,      &L[6144 + t * 8]);
    gload16(sA0 + 32, &L[8192 + t * 8]);
    gload16(sA1 + 32, &L[8192 + 2048 + t * 8]);
    gload16(sB0 + 32, &L[8192 + 4096 + t * 8]);
    gload16(sB1 + 32, &L[8192 + 6144 + t * 8]);
    asm volatile("s_waitcnt vmcnt(4)" ::: "memory");
    __builtin_amdgcn_sched_barrier(0);
    __builtin_amdgcn_s_barrier();
    __builtin_amdgcn_sched_barrier(0);

    for (int kt = 0; kt < KT; ++kt) {
        const bool pre = (kt + 2) < KT;
        if (pre) {
            ushort* bp2 = &L[((kt + 2) % 3) * 8192];
            const int ko = (kt + 2) << 5;
            gload16(sA0 + ko, bp2 + t * 8);
            gload16(sA1 + ko, bp2 + 2048 + t * 8);
            gload16(sB0 + ko, bp2 + 4096 + t * 8);
            gload16(sB1 + ko, bp2 + 6144 + t * 8);
        }
        const ushort* bp = &L[(kt % 3) * 8192];
        bf16x8 af[4], bw[4];
        #pragma unroll
        for (int mi = 0; mi < 4; mi++) af[mi] = *(const bf16x8*)(bp + offA[mi]);
        #pragma unroll
        for (int ni = 0; ni < 4; ni++) bw[ni] = *(const bf16x8*)(bp + offB[ni]);
        __builtin_amdgcn_s_setprio(1);
        #pragma unroll
        for (int mi = 0; mi < 4; mi++)
            #pragma unroll
            for (int ni = 0; ni < 4; ni++)
                acc[mi][ni] = __builtin_amdgcn_mfma_f32_16x16x32_bf16(af[mi], bw[ni], acc[mi][ni], 0, 0, 0);
        __builtin_amdgcn_s_setprio(0);
        if (pre) { asm volatile("s_waitcnt vmcnt(4)" ::: "memory"); }
        else     { asm volatile("s_waitcnt vmcnt(0)" ::: "memory"); }
        __builtin_amdgcn_sched_barrier(0);
        __builtin_amdgcn_s_barrier();
        __builtin_amdgcn_sched_barrier(0);
    }

    #pragma unroll
    for (int mi = 0; mi < 4; mi++)
        #pragma unroll
        for (int ni = 0; ni < 4; ni++)
            #pragma unroll
            for (int rr = 0; rr < 4; rr++) {
                const int row = row0 + wr * 64 + mi * 16 + l4 * 4 + rr;
                const int col = col0 + wc * 64 + ni * 16 + l15;
                C0[(size_t)row * ldc + col] = acc[mi][ni][rr];
            }
}

// ---------------- scan phase 1: inline dt + fused conv + per-chunk local end-state ----------------
__global__ __launch_bounds__(256) void scan_local(const ushort* __restrict__ Ub,
                                                  const float* __restrict__ DBC,
                                                  const float* __restrict__ W_dt,
                                                  const float* __restrict__ dt_bias,
                                                  const float* __restrict__ A_log,
                                                  const float* __restrict__ cw,
                                                  const float* __restrict__ cb,
                                                  float* __restrict__ hloc,
                                                  float* __restrict__ Pc) {
    const int c = blockIdx.x, h = blockIdx.y;
    const int pidx = threadIdx.x;
    const int ch = h * PH + pidx;
    const int t0 = c * LC;
    __shared__ float sdt[LC];
    __shared__ float sdA[LC][DSTATE];
    __shared__ float sdB[LC][DSTATE];
    const int st = pidx >> 4, sn = pidx & 15;

    if (pidx < LC) {   // dt head: dot64 + softplus + clip
        const float* row = DBC + (size_t)(t0 + pidx) * 320;
        const float* wd = W_dt + h * DTRANK;
        float acc = dt_bias[h];
        #pragma unroll 16
        for (int r2 = 0; r2 < DTRANK; r2++) acc = fmaf(row[r2], wd[r2], acc);
        float sp = acc > 20.f ? acc : log1pf(expf(acc));
        sdt[pidx] = fminf(fmaxf(sp, 1e-4f), 1.0f);
    }
    const float w0 = cw[ch * 4], w1 = cw[ch * 4 + 1], w2 = cw[ch * 4 + 2], w3 = cw[ch * 4 + 3];
    const float bia = cb[ch];
    const int bs = (c / NCB) * MB_ROWS;
    float um3 = (t0 - 3 >= bs) ? bf2f(Ub[(size_t)(t0 - 3) * DINNER + ch]) : 0.f;
    float um2 = (t0 - 2 >= bs) ? bf2f(Ub[(size_t)(t0 - 2) * DINNER + ch]) : 0.f;
    float um1 = (t0 - 1 >= bs) ? bf2f(Ub[(size_t)(t0 - 1) * DINNER + ch]) : 0.f;
    __syncthreads();

    {   // coefficient staging with inline dA = exp(dt * -exp(A_log))
        const float nA = -expf(A_log[h * DSTATE + sn]);
        #pragma unroll
        for (int j = 0; j < 4; j++) {
            int tt = st + j * 16;
            size_t trow = (size_t)(t0 + tt);
            float dv = sdt[tt];
            sdA[tt][sn] = expf(dv * nA);
            sdB[tt][sn] = dv * DBC[trow * 320 + 64 + h * DSTATE + sn];
        }
    }
    __syncthreads();

    float hst[DSTATE] = {};
    for (int t = 0; t < LC; t++) {
        float u0 = bf2f(Ub[(size_t)(t0 + t) * DINNER + ch]);
        float up = fmaf(w3, u0, fmaf(w2, um1, fmaf(w1, um2, fmaf(w0, um3, bia))));
        um3 = um2; um2 = um1; um1 = u0;
        #pragma unroll
        for (int n = 0; n < DSTATE; n++)
            hst[n] = fmaf(hst[n], sdA[t][n], up * sdB[t][n]);
    }
    float* hl = hloc + (((size_t)c * NH + h) * PH + pidx) * DSTATE;
    #pragma unroll
    for (int n = 0; n < DSTATE; n++) hl[n] = hst[n];

    if (pidx < DSTATE) {
        float pr = 1.f;
        for (int t = 0; t < LC; t++) pr *= sdA[t][pidx];
        Pc[((size_t)c * NH + h) * DSTATE + pidx] = pr;
    }
}

// ---------------- scan phase 2: serial carry across chunks (per batch) ----------------
__global__ __launch_bounds__(256) void scan_carry(const float* __restrict__ hloc,
                                                  const float* __restrict__ Pc,
                                                  float* __restrict__ Hent) {
    int g = blockIdx.x * 256 + threadIdx.x;
    int b = g >> 15;
    int r = g & 32767;
    int h = r >> 12;
    int inner = r & 4095;
    int n = r & 15;
    float carry = 0.f;
    for (int i = 0; i < NCB; i++) {
        int c = b * NCB + i;
        size_t idx = ((size_t)c * NH + h) * (PH * DSTATE) + inner;
        Hent[idx] = carry;
        carry = fmaf(Pc[((size_t)c * NH + h) * DSTATE + n], carry, hloc[idx]);
    }
}

// ---------------- scan phase 3: inline dt + conv + re-run chunk + skip + silu gate + residual ----------------
__global__ __launch_bounds__(256) void scan_out(const ushort* __restrict__ Zb,
                                                const ushort* __restrict__ Ub,
                                                const ushort* __restrict__ RESb,
                                                ushort* __restrict__ Yb,
                                                const float* __restrict__ DBC,
                                                const float* __restrict__ W_dt,
                                                const float* __restrict__ dt_bias,
                                                const float* __restrict__ A_log,
                                                const float* __restrict__ cw,
                                                const float* __restrict__ cb,
                                                const float* __restrict__ Dskip,
                                                const float* __restrict__ Hent) {
    const int c = blockIdx.x, h = blockIdx.y;
    const int pidx = threadIdx.x;
    const int ch = h * PH + pidx;
    const int t0 = c * LC;
    __shared__ float sdt[LC];
    __shared__ float sdA[LC][DSTATE];
    __shared__ float sdB[LC][DSTATE];
    __shared__ float sC [LC][DSTATE];
    const int st = pidx >> 4, sn = pidx & 15;

    if (pidx < LC) {
        const float* row = DBC + (size_t)(t0 + pidx) * 320;
        const float* wd = W_dt + h * DTRANK;
        float acc = dt_bias[h];
        #pragma unroll 16
        for (int r2 = 0; r2 < DTRANK; r2++) acc = fmaf(row[r2], wd[r2], acc);
        float sp = acc > 20.f ? acc : log1pf(expf(acc));
        sdt[pidx] = fminf(fmaxf(sp, 1e-4f), 1.0f);
    }
    const float w0 = cw[ch * 4], w1 = cw[ch * 4 + 1], w2 = cw[ch * 4 + 2], w3 = cw[ch * 4 + 3];
    const float bia = cb[ch];
    const int bs = (c / NCB) * MB_ROWS;
    float um3 = (t0 - 3 >= bs) ? bf2f(Ub[(size_t)(t0 - 3) * DINNER + ch]) : 0.f;
    float um2 = (t0 - 2 >= bs) ? bf2f(Ub[(size_t)(t0 - 2) * DINNER + ch]) : 0.f;
    float um1 = (t0 - 1 >= bs) ? bf2f(Ub[(size_t)(t0 - 1) * DINNER + ch]) : 0.f;
    __syncthreads();

    {
        const float nA = -expf(A_log[h * DSTATE + sn]);
        #pragma unroll
        for (int j = 0; j < 4; j++) {
            int tt = st + j * 16;
            size_t trow = (size_t)(t0 + tt);
            float dv = sdt[tt];
            sdA[tt][sn] = expf(dv * nA);
            sdB[tt][sn] = dv * DBC[trow * 320 + 64 + h * DSTATE + sn];
            sC [tt][sn] =      DBC[trow * 320 + 192 + h * DSTATE + sn];
        }
    }
    const float dsk = Dskip[ch];
    float hst[DSTATE];
    const float* he = Hent + (((size_t)c * NH + h) * PH + pidx) * DSTATE;
    #pragma unroll
    for (int n = 0; n < DSTATE; n++) hst[n] = he[n];
    __syncthreads();

    for (int t = 0; t < LC; t++) {
        size_t off = (size_t)(t0 + t) * DINNER + ch;
        float u0 = bf2f(Ub[off]);
        float up = fmaf(w3, u0, fmaf(w2, um1, fmaf(w1, um2, fmaf(w0, um3, bia))));
        um3 = um2; um2 = um1; um1 = u0;
        float a0 = 0.f, a1 = 0.f, a2 = 0.f, a3 = 0.f;
        #pragma unroll
        for (int n = 0; n < 4; n++) {
            hst[n +  0] = fmaf(hst[n +  0], sdA[t][n +  0], up * sdB[t][n +  0]);
            hst[n +  4] = fmaf(hst[n +  4], sdA[t][n +  4], up * sdB[t][n +  4]);
            hst[n +  8] = fmaf(hst[n +  8], sdA[t][n +  8], up * sdB[t][n +  8]);
            hst[n + 12] = fmaf(hst[n + 12], sdA[t][n + 12], up * sdB[t][n + 12]);
            a0 = fmaf(hst[n +  0], sC[t][n +  0], a0);
            a1 = fmaf(hst[n +  4], sC[t][n +  4], a1);
            a2 = fmaf(hst[n +  8], sC[t][n +  8], a2);
            a3 = fmaf(hst[n + 12], sC[t][n + 12], a3);
        }
        float yv = ((a0 + a1) + (a2 + a3)) + dsk * up;
        float zv = bf2f(Zb[off]);
        float sil = zv / (1.f + expf(-zv));
        Yb[off] = f2bf(fmaf(yv, sil, bf2f(RESb[off])));
    }
}

// ---------------- RMSNorm (bf16 in), bf16 output ----------------
__global__ __launch_bounds__(256) void rmsnorm_bf(const ushort* __restrict__ Yb,
                                                  const float* __restrict__ norm_w,
                                                  ushort* __restrict__ Gb) {
    const int row = blockIdx.x;
    const ushort* r = Yb + (size_t)row * DINNER;
    const int c0 = threadIdx.x * 8;
    uint4 packed = *(const uint4*)(r + c0);
    float v[8];
    v[0] = bf2f((ushort)(packed.x & 0xffff)); v[1] = bf2f((ushort)(packed.x >> 16));
    v[2] = bf2f((ushort)(packed.y & 0xffff)); v[3] = bf2f((ushort)(packed.y >> 16));
    v[4] = bf2f((ushort)(packed.z & 0xffff)); v[5] = bf2f((ushort)(packed.z >> 16));
    v[6] = bf2f((ushort)(packed.w & 0xffff)); v[7] = bf2f((ushort)(packed.w >> 16));
    float ss = 0.f;
    #pragma unroll
    for (int i = 0; i < 8; i++) ss = fmaf(v[i], v[i], ss);
    #pragma unroll
    for (int off = 32; off > 0; off >>= 1) ss += __shfl_down(ss, off);
    __shared__ float red[4];
    if ((threadIdx.x & 63) == 0) red[threadIdx.x >> 6] = ss;
    __syncthreads();
    float tot = red[0] + red[1] + red[2] + red[3];
    float inv = rsqrtf(tot / (float)DINNER + 1e-6f);
    float4 w0 = *(const float4*)(norm_w + c0);
    float4 w1 = *(const float4*)(norm_w + c0 + 4);
    uint4 o;
    o.x = cvt2bf(v[0] * inv * w0.x, v[1] * inv * w0.y);
    o.y = cvt2bf(v[2] * inv * w0.z, v[3] * inv * w0.w);
    o.z = cvt2bf(v[4] * inv * w1.x, v[5] * inv * w1.y);
    o.w = cvt2bf(v[6] * inv * w1.z, v[7] * inv * w1.w);
    *(uint4*)(Gb + (size_t)row * DINNER + c0) = o;
}

// ---------------- workspace layout ----------------
struct Lay {
    float *DBC, *PC, *HLOC, *HENT;
    ushort *YB, *ZB, *UB, *RESB, *XBF, *WB;
    size_t total;
};
static Lay mk_layout(char* base, int Mr) {
    size_t o = 0;
    auto take = [&](size_t bytes) { char* p = base + o; o = (o + bytes + 255) & ~(size_t)255; return p; };
    Lay l;
    l.YB   = (ushort*)take((size_t)Mr * 2048 * 2);
    l.DBC  = (float*) take((size_t)Mr * 320 * 4);
    l.PC   = (float*) take((size_t)(Mr / 64) * NH * DSTATE * 4);
    l.HLOC = (float*) take((size_t)Mr * 512 * 4);
    l.HENT = (float*) take((size_t)Mr * 512 * 4);
    l.ZB   = (ushort*)take((size_t)Mr * 2048 * 2);
    l.UB   = (ushort*)take((size_t)Mr * 2048 * 2);
    l.RESB = (ushort*)take((size_t)Mr * 2048 * 2);
    l.XBF  = (ushort*)take((size_t)8192 * 1024 * 2);
    l.WB   = (ushort*)take(((size_t)NTOT2 * 1024 + (size_t)1024 * 2048) * 2);
    l.total = o;
    return l;
}

extern "C" void kernel_launch(void* const* d_in, const int* in_sizes, int n_in,
                              void* d_out, int out_size, void* d_ws, size_t ws_size,
                              hipStream_t stream) {
    const float* x       = (const float*)d_in[0];
    const float* W_in    = (const float*)d_in[1];
    const float* W_dt    = (const float*)d_in[2];
    const float* conv_w  = (const float*)d_in[3];
    const float* conv_b  = (const float*)d_in[4];
    const float* A_log   = (const float*)d_in[5];
    const float* Dskip   = (const float*)d_in[6];
    const float* dt_bias = (const float*)d_in[7];
    const float* norm_w  = (const float*)d_in[8];
    const float* W_out   = (const float*)d_in[9];
    const float* W_res   = (const float*)d_in[10];
    float* out = (float*)d_out;

    Lay probe = mk_layout(nullptr, 2 * MB_ROWS);
    const bool fat = ws_size >= probe.total;
    const int Mr = fat ? 2 * MB_ROWS : MB_ROWS;
    const int npass = fat ? 1 : 2;
    const int nbc = fat ? 2 : 1;
    Lay l = mk_layout((char*)d_ws, Mr);

    ushort* wcat = l.WB;                                  // repacked [Z|U|RES|DBC] 6528 x 1024
    ushort* wotb = wcat + (size_t)NTOT2 * 1024;           // W_out 1024 x 2048
    ushort* Gb   = l.ZB;                                  // Z dead after scan_out; reuse for g

    // one fused conversion: weights (repacked) + W_out + x
    {
        const size_t total_gran = ((size_t)NTOT2 * 1024 + (size_t)1024 * 2048 + (size_t)8192 * 1024) / 8;
        cvt_all<<<(int)(total_gran / 256), 256, 0, stream>>>(W_in, W_res, W_out, x, l.WB, l.XBF);
    }

    for (int b = 0; b < npass; b++) {
        const ushort* xb = l.XBF + (size_t)b * MB_ROWS * DMODEL;
        float* outb = out + (size_t)b * MB_ROWS * DMODEL;

        // 1. fused in-proj + residual GEMM -> Zb | Ub | RESb | DBC   (Mr x 6528 x 1024)
        gemm_fused<<<51 * (Mr / 256), 512, 0, stream>>>(xb, wcat, l.ZB, l.UB, l.RESB, l.DBC, 51, DMODEL);
        // 2. chunk-parallel scan (inline dt, fused conv); y*silu(z)+res -> Yb (bf16)
        scan_local<<<dim3(Mr / LC, NH), 256, 0, stream>>>(l.UB, l.DBC, W_dt, dt_bias, A_log,
                                                          conv_w, conv_b, l.HLOC, l.PC);
        scan_carry<<<nbc * 128, 256, 0, stream>>>(l.HLOC, l.PC, l.HENT);
        scan_out<<<dim3(Mr / LC, NH), 256, 0, stream>>>(l.ZB, l.UB, l.RESB, l.YB, l.DBC,
                                                        W_dt, dt_bias, A_log,
                                                        conv_w, conv_b, Dskip, l.HENT);
        // 3. RMSNorm (bf16 in) -> bf16 g
        rmsnorm_bf<<<Mr, 256, 0, stream>>>(l.YB, norm_w, Gb);
        // 4. out-projection: out = g @ W_out^T (fp32 out), 128x128 tiles
        gemm_out128<<<8 * (Mr / 128), 256, 0, stream>>>(Gb, wotb, outb, 8, DINNER, DMODEL);
    }
}